// Round 13
// baseline (1819.391 us; speedup 1.0000x reference)
//
#include <hip/hip_runtime.h>
#include <hip/hip_bf16.h>

// GINet forward, fp32 in/out. R27 = R26 + wave-per-node k_agg: the 80-thread
// node-groups straddled wave boundaries (tn=tid/80) -> divergent edge loops
// (wave runs max(deg0,deg1) iters) and split gathers. Now 512-thr block = 8
// waves = 8 nodes; lane owns cols [4L,4L+4), lanes 0-10 also [256+4L), lanes
// 11-15 write the 300..319 zero pads. Edge loop wave-uniform; eidxp load is
// same-address (one fetch); P-row gather = one coalesced 512B+88B wave txn.
// Accumulation order per column unchanged -> bit-identical numerics.
// k_mlp2 frozen at structural floor (R26 verdict: writes were latency-hidden).

#define NN   100000
#define EE   200000
#define GG   2000
#define DD   300
#define D2   600
#define LL   5
#define FEATN 512
#define OUT2 256
#define ROWS_PER 256
#define RPB  48          // rows per k_mlp2 block
#define MLP_LDS (RPB * 632 * 2)   // 60,672 B -> 2 blocks/CU

typedef __hip_bfloat16 bf16;
typedef short vec8s __attribute__((ext_vector_type(8)));
typedef short vec4s __attribute__((ext_vector_type(4)));
typedef float vec4f __attribute__((ext_vector_type(4)));

__device__ __forceinline__ short f2bs(float v) {
    bf16 h = __float2bfloat16(v);
    return __builtin_bit_cast(short, h);
}
__device__ __forceinline__ float bs2f(short s) {
    unsigned u = ((unsigned)(unsigned short)s) << 16;
    return __builtin_bit_cast(float, u);
}

// ---- weight prepack: src[K][N] fp32 -> dst[kt][col<NPAD][32] bf16 ----
// batched over blockIdx.y (layer); strides in elements
__global__ void k_pack(const float* __restrict__ src0, short* __restrict__ dst0,
                       int Ksrc, int Nsrc, int KT, int NPAD,
                       size_t sstride, size_t dstride)
{
    const float* src = src0 + (size_t)blockIdx.y * sstride;
    short* dst = dst0 + (size_t)blockIdx.y * dstride;
    int idx = blockIdx.x * 256 + threadIdx.x;
    int total = KT * NPAD * 32;
    if (idx >= total) return;
    int col = idx % NPAD;
    int tmp = idx / NPAD;
    int kk  = tmp % 32;
    int kt  = tmp / 32;
    int k = kt * 32 + kk;
    short v = 0;
    if (k < Ksrc && col < Nsrc) v = f2bs(src[(size_t)k * Nsrc + col]);
    dst[((size_t)kt * NPAD + col) * 32 + kk] = v;
}

// ---- combined edge-emb tables: E[l][c][d], c<24 = a0*6+a1*2+a2, c==24 self ----
__global__ void k_etab(const float* __restrict__ edge_emb, float* __restrict__ E)
{
    int i = blockIdx.x * 256 + threadIdx.x;
    if (i >= LL * 25 * DD) return;
    int d = i % DD;
    int t = i / DD;
    int c = t % 25;
    int l = t / 25;
    int a0 = (c == 24) ? 4 : (c / 6);
    int a1 = (c == 24) ? 0 : ((c % 6) / 2);
    int a2 = (c == 24) ? 0 : (c % 2);
    const float* e0 = edge_emb + (size_t)((l * 3 + 0) * 5) * DD;
    const float* e1 = edge_emb + (size_t)((l * 3 + 1) * 5) * DD;
    const float* e2 = edge_emb + (size_t)((l * 3 + 2) * 5) * DD;
    E[i] = e0[a0 * DD + d] + e1[a1 * DD + d] + e2[a2 * DD + d];
}

// ---- repack EIDX: edge id -> src | (combo<<17) ----
__global__ void k_repack(int* __restrict__ eidx, const int* __restrict__ src,
                         const int* __restrict__ attr)
{
    int i = blockIdx.x * 256 + threadIdx.x;
    if (i >= EE) return;
    int e = eidx[i];
    int c = attr[e * 3] * 6 + attr[e * 3 + 1] * 2 + attr[e * 3 + 2];
    eidx[i] = src[e] | (c << 17);
}

// ---- fused MLP layer + replicated BN stats; 48 rows/block, 8 waves ----
__global__ __launch_bounds__(512, 4) void k_mlp2(
    const short* __restrict__ Qb, const short* __restrict__ W1P,
    const float* __restrict__ b1, const short* __restrict__ W2P,
    const float* __restrict__ b2, void* __restrict__ Pout, int f16out,
    float* __restrict__ RS)            // [2][32][600] partial sums for layer
{
    extern __shared__ __align__(16) char smem_c[];
    short* Apan = (short*)smem_c;                 // 48 rows x 320 shorts, swizzled
    short (*Hl)[632] = (short(*)[632])smem_c;     // overlaps Apan (A dead first)

    const int t = threadIdx.x;
    const int wv = t >> 6, lane = t & 63;
    const int m = lane & 15, quad = lane >> 4;
    const int rb = (int)blockIdx.x * RPB;
    const int rep = ((int)blockIdx.x & 31) * 600;

    // ---- stage A-panel: global_load_lds, source-swizzled (chunk ^= row&7) ----
    {
        const short* qbase = Qb + (size_t)rb * 320;
#pragma unroll
        for (int i = 0; i < 4; i++) {
            int j = i * 8 + wv;                       // 1KB issue index, j < 30
            if (j < 30) {
                int c   = j * 64 + lane;              // 16B chunk index
                int c8  = c >> 3;
                int row = c8 / 5;
                int ch  = (c8 - row * 5) * 8 + (lane & 7);
                const short* src = qbase + (size_t)row * 320
                                 + (size_t)((ch ^ (row & 7)) * 8);
                __builtin_amdgcn_global_load_lds(
                    (const __attribute__((address_space(1))) unsigned int*)src,
                    (__attribute__((address_space(3))) unsigned int*)(smem_c + j * 1024),
                    16, 0, 0);
            }
        }
    }

    // per-lane swizzled A-read bases (shorts): parity-split on eh = (m>>2)&1
    const int ql   = quad ^ (m & 3);
    const int eh   = (m >> 2) & 1;
    const int abE  = m * 320 + ql * 8 + eh * 32;        // even kt base
    const int abO  = m * 320 + ql * 8 + (1 - eh) * 32;  // odd kt base

    vec4f acc1[3][5];
#pragma unroll
    for (int g = 0; g < 3; g++)
#pragma unroll
        for (int cf = 0; cf < 5; cf++) acc1[g][cf] = (vec4f)0.f;

    // ---- stage 1: Hl = relu(Qb @ W1 + b1), operand-swapped MFMA ----
    const short* w1b = W1P + ((size_t)(wv * 80 + m) * 32) + quad * 8;
    vec8s bcur[5], bnxt[5];
#pragma unroll
    for (int cf = 0; cf < 5; cf++) bcur[cf] = *(const vec8s*)(w1b + cf * 512);

    __syncthreads();   // A-panel DMA drained (vmcnt0 at barrier)

#pragma unroll
    for (int kt = 0; kt < 10; kt++) {
        if (kt < 9) {
            const short* wn = w1b + (size_t)(kt + 1) * 20480;
#pragma unroll
            for (int cf = 0; cf < 5; cf++) bnxt[cf] = *(const vec8s*)(wn + cf * 512);
        }
        const int base = (kt & 1) ? abO : abE;
        const int koff = (kt & ~1) * 32;
        vec8s af[3];
#pragma unroll
        for (int g = 0; g < 3; g++)
            af[g] = *(const vec8s*)(Apan + base + koff + g * 5120);
        __builtin_amdgcn_s_setprio(1);
#pragma unroll
        for (int cf = 0; cf < 5; cf++)
#pragma unroll
            for (int g = 0; g < 3; g++)
                acc1[g][cf] = __builtin_amdgcn_mfma_f32_16x16x32_bf16(
                    bcur[cf], af[g], acc1[g][cf], 0, 0, 0);
        __builtin_amdgcn_s_setprio(0);
#pragma unroll
        for (int cf = 0; cf < 5; cf++) bcur[cf] = bnxt[cf];
    }

    // prefetch stage-2 B tiles 0 and 1 (global, independent of LDS)
    const short* w2b = W2P + ((size_t)(wv * 48 + m) * 32) + quad * 8;
    vec8s b2f[2][3];
#pragma unroll
    for (int cf = 0; cf < 3; cf++) {
        b2f[0][cf] = *(const vec8s*)(w2b + cf * 512);
        b2f[1][cf] = *(const vec8s*)(w2b + 12288 + cf * 512);
    }

    __syncthreads();   // all A-panel reads done before Hl overwrites region

    // stage-1 epilogue: bias+relu+bf16; lane holds 4 consecutive cols of a row
#pragma unroll
    for (int g = 0; g < 3; g++) {
#pragma unroll
        for (int cf = 0; cf < 5; cf++) {
            const int col0 = wv * 80 + cf * 16 + quad * 4;
            if (col0 < 600) {
                vec4f bv = *(const vec4f*)(b1 + col0);
                vec4s o;
#pragma unroll
                for (int r = 0; r < 4; r++)
                    o[r] = f2bs(fmaxf(acc1[g][cf][r] + bv[r], 0.f));
                *(vec4s*)&Hl[g * 16 + m][col0] = o;
            } else if (col0 < 608) {
                *(vec4s*)&Hl[g * 16 + m][col0] = (vec4s)0;
            }
        }
    }
    __syncthreads();

    // ---- stage 2 + stats into replica; staged coalesced P write ----
    {
        vec4f acc2[3][3];
#pragma unroll
        for (int g = 0; g < 3; g++)
#pragma unroll
            for (int cf = 0; cf < 3; cf++) acc2[g][cf] = (vec4f)0.f;

#pragma unroll
        for (int kt = 0; kt < 19; kt++) {
            vec8s ha[3];
#pragma unroll
            for (int g = 0; g < 3; g++)
                ha[g] = *(const vec8s*)&Hl[g * 16 + m][kt * 32 + quad * 8];
            __builtin_amdgcn_s_setprio(1);
#pragma unroll
            for (int cf = 0; cf < 3; cf++)
#pragma unroll
                for (int g = 0; g < 3; g++)
                    acc2[g][cf] = __builtin_amdgcn_mfma_f32_16x16x32_bf16(
                        ha[g], b2f[kt & 1][cf], acc2[g][cf], 0, 0, 0);
            __builtin_amdgcn_s_setprio(0);
            if (kt < 17) {
                const short* wn = w2b + (size_t)(kt + 2) * 12288;
#pragma unroll
                for (int cf = 0; cf < 3; cf++)
                    b2f[kt & 1][cf] = *(const vec8s*)(wn + cf * 512);
            }
        }

        __syncthreads();   // Hl reads complete; region reused for staged P

        short* Ps  = (short*)smem_c;   // [48][300] bf16 (28.8KB)
        float* Pw  = (float*)smem_c;   // [48][300] fp32 (57.6KB <= 60.6KB)

#pragma unroll
        for (int cf = 0; cf < 3; cf++) {
            int gc = wv * 48 + cf * 16 + m;
            bool ok = (gc < DD);
            float bv = ok ? b2[gc] : 0.f;
            float s = 0.f, q = 0.f;
#pragma unroll
            for (int g = 0; g < 3; g++) {
#pragma unroll
                for (int reg = 0; reg < 4; reg++) {
                    int rl = g * 16 + quad * 4 + reg;
                    bool vr = (rb + rl) < NN;
                    float v = acc2[g][cf][reg] + bv;
                    if (ok) {
                        if (f16out) Ps[rl * 300 + gc] = f2bs(v);
                        else        Pw[rl * 300 + gc] = v;
                    }
                    if (vr) { s += v; q += v * v; }
                }
            }
            s += __shfl_xor(s, 16); s += __shfl_xor(s, 32);
            q += __shfl_xor(q, 16); q += __shfl_xor(q, 32);
            if (ok && quad == 0) {
                atomicAdd(&RS[rep + gc], s);
                atomicAdd(&RS[19200 + rep + gc], q);
            }
        }
        __syncthreads();

        // coalesced linear copy LDS -> Pout (block's rows are contiguous)
        int nrows = NN - rb; if (nrows > RPB) nrows = RPB;
        int total4 = nrows * 300 / 4;
        if (f16out) {
            short* dst = (short*)Pout + (size_t)rb * 300;
            for (int i = t; i < total4; i += 512)
                *(vec4s*)(dst + i * 4) = *(const vec4s*)(Ps + i * 4);
        } else {
            float* dst = (float*)Pout + (size_t)rb * 300;
            for (int i = t; i < total4; i += 512)
                *(vec4f*)(dst + i * 4) = *(const vec4f*)(Pw + i * 4);
        }
    }
}

// ---- embed GEMM, stage1 shape with A+B double-buffer: H = Qb @ OLWP + b ----
__global__ __launch_bounds__(256) void k_g1(
    const short* __restrict__ Qb, const short* __restrict__ WP,
    const float* __restrict__ bias, float* __restrict__ H)
{
    const int t = threadIdx.x;
    const int wv = t >> 6, lane = t & 63;
    const int m = lane & 15, quad = lane >> 4;
    const int rb = (int)blockIdx.x * 32;
    const short* arow0 = Qb + (size_t)(rb + m) * 320 + quad * 8;
    const short* arow1 = arow0 + (size_t)16 * 320;
    const short* wb0 = WP + ((size_t)(wv * 80 + m) * 32) + quad * 8;

    vec4f acc[2][5];
#pragma unroll
    for (int g = 0; g < 2; g++)
#pragma unroll
        for (int cf = 0; cf < 5; cf++) acc[g][cf] = (vec4f)0.f;

    vec8s af0 = *(const vec8s*)arow0;
    vec8s af1 = *(const vec8s*)arow1;
    vec8s bcur[5], bnxt[5];
#pragma unroll
    for (int cf = 0; cf < 5; cf++) bcur[cf] = *(const vec8s*)(wb0 + cf * 512);

#pragma unroll
    for (int kt = 0; kt < 10; kt++) {
        vec8s an0 = af0, an1 = af1;
        if (kt < 9) {
            an0 = *(const vec8s*)(arow0 + (kt + 1) * 32);
            an1 = *(const vec8s*)(arow1 + (kt + 1) * 32);
            const short* wn = wb0 + (size_t)(kt + 1) * 12288;
#pragma unroll
            for (int cf = 0; cf < 5; cf++) bnxt[cf] = *(const vec8s*)(wn + cf * 512);
        }
#pragma unroll
        for (int cf = 0; cf < 5; cf++) {
            acc[0][cf] = __builtin_amdgcn_mfma_f32_16x16x32_bf16(af0, bcur[cf], acc[0][cf], 0, 0, 0);
            acc[1][cf] = __builtin_amdgcn_mfma_f32_16x16x32_bf16(af1, bcur[cf], acc[1][cf], 0, 0, 0);
        }
        af0 = an0; af1 = an1;
#pragma unroll
        for (int cf = 0; cf < 5; cf++) bcur[cf] = bnxt[cf];
    }
#pragma unroll
    for (int cf = 0; cf < 5; cf++) {
        int gc = wv * 80 + cf * 16 + m;
        if (gc >= DD) continue;
        float bv = bias[gc];
#pragma unroll
        for (int g = 0; g < 2; g++)
#pragma unroll
            for (int reg = 0; reg < 4; reg++)
                H[(size_t)(rb + g * 16 + quad * 4 + reg) * DD + gc] = acc[g][cf][reg] + bv;
    }
}

// ============ CSR build ============
__global__ void k_degree(const int* __restrict__ dst, int* __restrict__ deg) {
    int e = blockIdx.x * 256 + threadIdx.x;
    if (e < EE) atomicAdd(&deg[dst[e]], 1);
}

__global__ void k_scan1(const int* __restrict__ deg, int* __restrict__ off,
                        int* __restrict__ bsum)
{
    __shared__ int s[256];
    int i = blockIdx.x * 256 + threadIdx.x;
    int v = (i < NN) ? deg[i] : 0;
    s[threadIdx.x] = v;
    __syncthreads();
    for (int o = 1; o < 256; o <<= 1) {
        int tv = (threadIdx.x >= o) ? s[threadIdx.x - o] : 0;
        __syncthreads();
        s[threadIdx.x] += tv;
        __syncthreads();
    }
    if (i < NN) off[i] = s[threadIdx.x] - v;
    if (threadIdx.x == 255) bsum[blockIdx.x] = s[255];
}

// parallel scan over nb (<512) block sums: one 512-thread block
__global__ void k_scan2(int* __restrict__ bsum, int* __restrict__ off, int nb) {
    __shared__ int ws[8];
    int t = threadIdx.x;
    int v = (t < nb) ? bsum[t] : 0;
    int s = v;
    for (int o = 1; o < 64; o <<= 1) {
        int u = __shfl_up(s, o, 64);
        if ((t & 63) >= o) s += u;
    }
    if ((t & 63) == 63) ws[t >> 6] = s;
    __syncthreads();
    if (t < 8) {
        int a = ws[t];
        for (int o = 1; o < 8; o <<= 1) {
            int u = __shfl_up(a, o, 64);
            if (t >= o) a += u;
        }
        ws[t] = a;
    }
    __syncthreads();
    int base = (t >> 6) ? ws[(t >> 6) - 1] : 0;
    int incl = s + base;
    if (t < nb) bsum[t] = incl - v;      // exclusive
    if (t == nb - 1) off[NN] = incl;     // total
}

__global__ void k_scan3(int* __restrict__ off, const int* __restrict__ bsum,
                        int* __restrict__ curs)
{
    int i = blockIdx.x * 256 + threadIdx.x;
    if (i >= NN) return;
    int v = off[i] + bsum[i >> 8];
    off[i] = v;
    curs[i] = v;
}

__global__ void k_fill(const int* __restrict__ dst, int* __restrict__ curs,
                       int* __restrict__ eidx)
{
    int e = blockIdx.x * 256 + threadIdx.x;
    if (e >= EE) return;
    int pos = atomicAdd(&curs[dst[e]], 1);
    eidx[pos] = e;
}

// ============ embed attention -> bf16 rows (stride 320, pads zeroed) ============
__global__ __launch_bounds__(256) void k_embed(
    const int* __restrict__ x, const float* __restrict__ atom_emb,
    const float* __restrict__ att_vec, short* __restrict__ fusedb)
{
    int wave = threadIdx.x >> 6;
    int lane = threadIdx.x & 63;
    int n = blockIdx.x * 4 + wave;
    if (n >= NN) return;

    float att[5];
#pragma unroll
    for (int j = 0; j < 5; j++) {
        int d = lane + 64 * j;
        att[j] = (d < DD) ? att_vec[d] : 0.f;
    }
    float emb[9][5];
    float sc[9];
#pragma unroll
    for (int f = 0; f < 9; f++) {
        int idx = x[n * 9 + f];
        const float* p = atom_emb + (size_t)(f * 119 + idx) * DD;
        float partial = 0.f;
#pragma unroll
        for (int j = 0; j < 5; j++) {
            int d = lane + 64 * j;
            float v = (d < DD) ? p[d] : 0.f;
            emb[f][j] = v;
            partial += v * att[j];
        }
#pragma unroll
        for (int off = 32; off; off >>= 1) partial += __shfl_xor(partial, off, 64);
        sc[f] = partial;
    }
    float mx = sc[0];
#pragma unroll
    for (int f = 1; f < 9; f++) mx = fmaxf(mx, sc[f]);
    float s = 0.f;
#pragma unroll
    for (int f = 0; f < 9; f++) { sc[f] = __expf(sc[f] - mx); s += sc[f]; }
    float inv = 1.f / s;
#pragma unroll
    for (int j = 0; j < 5; j++) {
        int d = lane + 64 * j;
        float acc = 0.f;
        if (d < DD) {
#pragma unroll
            for (int f = 0; f < 9; f++) acc += emb[f][j] * sc[f];
            acc *= inv;
        }
        fusedb[(size_t)n * 320 + d] = (d < DD) ? f2bs(acc) : (short)0;
    }
}

// ---- gaussian basis: 4 nodes/block x 80 thr, d4 grain ----
__global__ __launch_bounds__(320) void k_gaussg(
    const int* __restrict__ off, const int* __restrict__ eidx,
    const float* __restrict__ dist, const float* __restrict__ g_means,
    const float* __restrict__ g_stds, const float* __restrict__ scale_p,
    float* __restrict__ H)
{
    int tn = threadIdx.x / 80;
    int td = threadIdx.x - tn * 80;
    int n = blockIdx.x * 4 + tn;
    if (n >= NN) return;
    int d4 = td * 4;
    if (d4 >= DD) return;
    int beg = off[n], end = off[n + 1];
    if (beg == end) return;
    vec4f gs = *(const vec4f*)(g_stds + d4);
    vec4f gm = *(const vec4f*)(g_means + d4);
    float sd[4], mean[4], inva[4], sum[4];
#pragma unroll
    for (int j = 0; j < 4; j++) {
        sd[j] = fabsf(gs[j]) + 0.01f;
        mean[j] = gm[j];
        inva[j] = 1.f / (2.5066263f * sd[j]);
        sum[j] = 0.f;
    }
    for (int i = beg; i < end; i++) {
        float xv = dist[eidx[i]];
#pragma unroll
        for (int j = 0; j < 4; j++) {
            float z = (xv - mean[j]) / sd[j];
            sum[j] += __expf(-0.5f * z * z) * inva[j];
        }
    }
    int deg = end - beg;
    int c = deg - 1; c = c < 0 ? 0 : (c > 3 ? 3 : c);
    vec4f sp = *(const vec4f*)(scale_p + c * DD + d4);
    float* hp = H + (size_t)n * DD + d4;
    vec4f hv = *(const vec4f*)hp;
#pragma unroll
    for (int j = 0; j < 4; j++) hv[j] += __expf(sp[j]) * sum[j];
    *(vec4f*)hp = hv;
}

// ---- fused aggregation: wave-per-node (8 nodes / 512-thr block), 2-edge
//      batched gather issue. Lane owns cols [4L,4L+4); lanes 0-10 also own
//      [256+4L); lanes 11-15 write the 300..319 zero pads.
//      apply=0: fp32 P, apply=1: bf16 P ----
__global__ __launch_bounds__(512) void k_agg(
    const void* __restrict__ P, const int* __restrict__ off,
    const int* __restrict__ eidxp, const float* __restrict__ E,
    const float* __restrict__ scale, const float* __restrict__ shift,
    int apply, short* __restrict__ Qb)
{
    const int wv = threadIdx.x >> 6, lane = threadIdx.x & 63;
    const int n = (int)blockIdx.x * 8 + wv;
    if (n >= NN) return;                  // wave-uniform (grid exact anyway)
    const int dA = lane * 4;              // 0..252, always valid
    const int dB = 256 + lane * 4;        // valid (<300) for lane<11
    const bool hB = (dB < DD);

    const float* Pf = (const float*)P;
    const short* Ph = (const short*)P;

    float aA[4], aB[4];
    float scA[4], shA[4], scB[4], shB[4];
#pragma unroll
    for (int j = 0; j < 4; j++) { aB[j] = 0.f; scB[j] = 1.f; shB[j] = 0.f; }

    if (apply) {
        vec4f s4 = *(const vec4f*)(scale + dA);
        vec4f h4 = *(const vec4f*)(shift + dA);
#pragma unroll
        for (int j = 0; j < 4; j++) { scA[j] = s4[j]; shA[j] = h4[j]; }
        if (hB) {
            vec4f s4b = *(const vec4f*)(scale + dB);
            vec4f h4b = *(const vec4f*)(shift + dB);
#pragma unroll
            for (int j = 0; j < 4; j++) { scB[j] = s4b[j]; shB[j] = h4b[j]; }
        }
        vec4s pv = *(const vec4s*)(Ph + (size_t)n * 300 + dA);
#pragma unroll
        for (int j = 0; j < 4; j++)
            aA[j] = fmaxf(bs2f(pv[j]) * scA[j] + shA[j], 0.f);
        if (hB) {
            vec4s pvb = *(const vec4s*)(Ph + (size_t)n * 300 + dB);
#pragma unroll
            for (int j = 0; j < 4; j++)
                aB[j] = fmaxf(bs2f(pvb[j]) * scB[j] + shB[j], 0.f);
        }
    } else {
        vec4f pv = *(const vec4f*)(Pf + (size_t)n * DD + dA);
#pragma unroll
        for (int j = 0; j < 4; j++) aA[j] = pv[j];
        if (hB) {
            vec4f pvb = *(const vec4f*)(Pf + (size_t)n * DD + dB);
#pragma unroll
            for (int j = 0; j < 4; j++) aB[j] = pvb[j];
        }
    }
    {
        vec4f es = *(const vec4f*)(E + 24 * DD + dA);
#pragma unroll
        for (int j = 0; j < 4; j++) aA[j] += es[j];
        if (hB) {
            vec4f esb = *(const vec4f*)(E + 24 * DD + dB);
#pragma unroll
            for (int j = 0; j < 4; j++) aB[j] += esb[j];
        }
    }

    const int beg = off[n], end = off[n + 1];   // wave-uniform bounds
    int i = beg;
    if (apply) {
        for (; i + 1 < end; i += 2) {
            int v0 = eidxp[i], v1 = eidxp[i + 1];   // same-addr wave loads
            int s0 = v0 & 131071, c0 = v0 >> 17;
            int s1 = v1 & 131071, c1 = v1 >> 17;
            vec4s p0a = *(const vec4s*)(Ph + (size_t)s0 * 300 + dA);
            vec4s p1a = *(const vec4s*)(Ph + (size_t)s1 * 300 + dA);
            vec4f e0a = *(const vec4f*)(E + c0 * DD + dA);
            vec4f e1a = *(const vec4f*)(E + c1 * DD + dA);
            vec4s p0b = (vec4s)0, p1b = (vec4s)0;
            vec4f e0b = (vec4f)0.f, e1b = (vec4f)0.f;
            if (hB) {
                p0b = *(const vec4s*)(Ph + (size_t)s0 * 300 + dB);
                p1b = *(const vec4s*)(Ph + (size_t)s1 * 300 + dB);
                e0b = *(const vec4f*)(E + c0 * DD + dB);
                e1b = *(const vec4f*)(E + c1 * DD + dB);
            }
#pragma unroll
            for (int j = 0; j < 4; j++)
                aA[j] += fmaxf(bs2f(p0a[j]) * scA[j] + shA[j], 0.f) + e0a[j];
#pragma unroll
            for (int j = 0; j < 4; j++)
                aA[j] += fmaxf(bs2f(p1a[j]) * scA[j] + shA[j], 0.f) + e1a[j];
            if (hB) {
#pragma unroll
                for (int j = 0; j < 4; j++)
                    aB[j] += fmaxf(bs2f(p0b[j]) * scB[j] + shB[j], 0.f) + e0b[j];
#pragma unroll
                for (int j = 0; j < 4; j++)
                    aB[j] += fmaxf(bs2f(p1b[j]) * scB[j] + shB[j], 0.f) + e1b[j];
            }
        }
        if (i < end) {
            int v0 = eidxp[i];
            int s0 = v0 & 131071, c0 = v0 >> 17;
            vec4s p0a = *(const vec4s*)(Ph + (size_t)s0 * 300 + dA);
            vec4f e0a = *(const vec4f*)(E + c0 * DD + dA);
#pragma unroll
            for (int j = 0; j < 4; j++)
                aA[j] += fmaxf(bs2f(p0a[j]) * scA[j] + shA[j], 0.f) + e0a[j];
            if (hB) {
                vec4s p0b = *(const vec4s*)(Ph + (size_t)s0 * 300 + dB);
                vec4f e0b = *(const vec4f*)(E + c0 * DD + dB);
#pragma unroll
                for (int j = 0; j < 4; j++)
                    aB[j] += fmaxf(bs2f(p0b[j]) * scB[j] + shB[j], 0.f) + e0b[j];
            }
        }
    } else {
        for (; i + 1 < end; i += 2) {
            int v0 = eidxp[i], v1 = eidxp[i + 1];
            int s0 = v0 & 131071, c0 = v0 >> 17;
            int s1 = v1 & 131071, c1 = v1 >> 17;
            vec4f p0a = *(const vec4f*)(Pf + (size_t)s0 * DD + dA);
            vec4f p1a = *(const vec4f*)(Pf + (size_t)s1 * DD + dA);
            vec4f e0a = *(const vec4f*)(E + c0 * DD + dA);
            vec4f e1a = *(const vec4f*)(E + c1 * DD + dA);
            vec4f p0b = (vec4f)0.f, p1b = (vec4f)0.f;
            vec4f e0b = (vec4f)0.f, e1b = (vec4f)0.f;
            if (hB) {
                p0b = *(const vec4f*)(Pf + (size_t)s0 * DD + dB);
                p1b = *(const vec4f*)(Pf + (size_t)s1 * DD + dB);
                e0b = *(const vec4f*)(E + c0 * DD + dB);
                e1b = *(const vec4f*)(E + c1 * DD + dB);
            }
#pragma unroll
            for (int j = 0; j < 4; j++) aA[j] += p0a[j] + e0a[j];
#pragma unroll
            for (int j = 0; j < 4; j++) aA[j] += p1a[j] + e1a[j];
            if (hB) {
#pragma unroll
                for (int j = 0; j < 4; j++) aB[j] += p0b[j] + e0b[j];
#pragma unroll
                for (int j = 0; j < 4; j++) aB[j] += p1b[j] + e1b[j];
            }
        }
        if (i < end) {
            int v0 = eidxp[i];
            int s0 = v0 & 131071, c0 = v0 >> 17;
            vec4f p0a = *(const vec4f*)(Pf + (size_t)s0 * DD + dA);
            vec4f e0a = *(const vec4f*)(E + c0 * DD + dA);
#pragma unroll
            for (int j = 0; j < 4; j++) aA[j] += p0a[j] + e0a[j];
            if (hB) {
                vec4f p0b = *(const vec4f*)(Pf + (size_t)s0 * DD + dB);
                vec4f e0b = *(const vec4f*)(E + c0 * DD + dB);
#pragma unroll
                for (int j = 0; j < 4; j++) aB[j] += p0b[j] + e0b[j];
            }
        }
    }

    {
        vec4s oA;
#pragma unroll
        for (int j = 0; j < 4; j++) oA[j] = f2bs(aA[j]);
        *(vec4s*)&Qb[(size_t)n * 320 + dA] = oA;
    }
    if (hB) {
        vec4s oB;
#pragma unroll
        for (int j = 0; j < 4; j++) oB[j] = f2bs(aB[j]);
        *(vec4s*)&Qb[(size_t)n * 320 + dB] = oB;
    } else if (lane >= 11 && lane < 16) {
        // dB = 300..316: exactly the 20 pad shorts 300..319
        *(vec4s*)&Qb[(size_t)n * 320 + dB] = (vec4s)0;
    }
}

// ---- reduce 32 replicas -> scale/shift for the layer ----
__global__ void k_bnprep(const float* __restrict__ RS, float* __restrict__ SC,
                         const float* __restrict__ gamma,
                         const float* __restrict__ beta)
{
    int d = threadIdx.x + blockIdx.x * 256;
    if (d >= DD) return;
    float s = 0.f, q = 0.f;
    for (int r = 0; r < 32; r++) {
        s += RS[r * 600 + d];
        q += RS[19200 + r * 600 + d];
    }
    float mu = s * (1.f / NN);
    float var = q * (1.f / NN) - mu * mu;
    var = fmaxf(var, 0.f);
    float sc = gamma[d] * rsqrtf(var + 1e-5f);
    SC[d] = sc;
    SC[600 + d] = beta[d] - mu * sc;
}

// ============ pooling (with fused run-length counting) + head ============
__global__ __launch_bounds__(320) void k_pool(const float* __restrict__ H,
                                              const int* __restrict__ batch,
                                              float* __restrict__ HG,
                                              float* __restrict__ cnt)
{
    __shared__ int sb[ROWS_PER];
    int r0 = blockIdx.x * ROWS_PER;
    int rend = min(r0 + ROWS_PER, NN);
    for (int i = threadIdx.x; i < rend - r0; i += 320) sb[i] = batch[r0 + i];
    __syncthreads();
    int d = threadIdx.x;
    if (d >= DD) return;
    int cur = sb[0];
    float acc = 0.f;
    int run = 0;
    for (int r = r0; r < rend; r++) {
        int b = sb[r - r0];
        if (b != cur) {
            atomicAdd(&HG[(size_t)cur * DD + d], acc);
            if (d == 0) atomicAdd(&cnt[cur], (float)run);
            acc = 0.f; run = 0; cur = b;
        }
        acc += H[(size_t)r * DD + d];
        run++;
    }
    atomicAdd(&HG[(size_t)cur * DD + d], acc);
    if (d == 0) atomicAdd(&cnt[cur], (float)run);
}

__global__ void k_hgdiv(float* __restrict__ HG, const float* __restrict__ cnt,
                        const float* __restrict__ SC)
{
    int idx = blockIdx.x * 256 + threadIdx.x;
    if (idx >= GG * DD) return;
    int d = idx % DD;
    float mean = HG[idx] / fmaxf(cnt[idx / DD], 1.0f);
    HG[idx] = mean * SC[d] + SC[600 + d];
}

// ---- head GEMM: 16x64 tile, 1x4 outputs/thread, high occupancy ----
__global__ __launch_bounds__(256) void k_gemm(
    const float* __restrict__ A, const float* __restrict__ W,
    const float* __restrict__ bias, float* __restrict__ Cf,
    float* __restrict__ Cout, int M, int K, int Ncol, int relu)
{
    __shared__ float Ash[16][33];
    const int tx = threadIdx.x & 15;        // col group (float4)
    const int ty = threadIdx.x >> 4;        // row 0..15
    const int rb = blockIdx.y * 16;
    const int col = blockIdx.x * 64 + tx * 4;

    float acc[4] = {0.f, 0.f, 0.f, 0.f};

    for (int k0 = 0; k0 < K; k0 += 32) {
        // stage A[rb..rb+16)[k0..k0+32) -> Ash (256 thr x 2 floats)
        {
            int r  = threadIdx.x >> 4;
            int kk = (threadIdx.x & 15) * 2;
            int row = rb + r;
            float vx = 0.f, vy = 0.f;
            if (row < M) {
                const float* ap = A + (size_t)row * K + k0 + kk;
                if (k0 + kk + 1 < K) {
                    float2 v = *(const float2*)ap;
                    vx = v.x; vy = v.y;
                } else if (k0 + kk < K) {
                    vx = ap[0];
                }
            }
            Ash[r][kk]     = vx;
            Ash[r][kk + 1] = vy;
        }
        __syncthreads();

        const int kmax = (K - k0 < 32) ? (K - k0) : 32;
        const float* wp = W + (size_t)k0 * Ncol + col;
#pragma unroll 4
        for (int k = 0; k < kmax; k++) {
            float4 wv = *(const float4*)(wp + (size_t)k * Ncol);
            float a = Ash[ty][k];
            acc[0] += a * wv.x; acc[1] += a * wv.y;
            acc[2] += a * wv.z; acc[3] += a * wv.w;
        }
        __syncthreads();
    }

    int row = rb + ty;
    if (row < M) {
        float4 bv = *(const float4*)(bias + col);
        float4 o;
        o.x = acc[0] + bv.x; o.y = acc[1] + bv.y;
        o.z = acc[2] + bv.z; o.w = acc[3] + bv.w;
        if (relu) {
            o.x = fmaxf(o.x, 0.f); o.y = fmaxf(o.y, 0.f);
            o.z = fmaxf(o.z, 0.f); o.w = fmaxf(o.w, 0.f);
        }
        if (Cf)   *(float4*)(Cf   + (size_t)row * Ncol + col) = o;
        if (Cout) *(float4*)(Cout + (size_t)row * Ncol + col) = o;
    }
}

extern "C" void kernel_launch(void* const* d_in, const int* in_sizes, int n_in,
                              void* d_out, int out_size, void* d_ws, size_t ws_size,
                              hipStream_t stream)
{
    const int*   x          = (const int*)  d_in[0];
    const int*   edge_index = (const int*)  d_in[1];
    const int*   edge_attr  = (const int*)  d_in[2];
    const float* edge_dist  = (const float*)d_in[3];
    const int*   batch      = (const int*)  d_in[4];
    const float* atom_emb   = (const float*)d_in[5];
    const float* att_vec    = (const float*)d_in[6];
    const float* out_lin_w  = (const float*)d_in[7];
    const float* out_lin_b  = (const float*)d_in[8];
    const float* g_means    = (const float*)d_in[9];
    const float* g_stds     = (const float*)d_in[10];
    const float* scale_p    = (const float*)d_in[11];
    const float* edge_emb   = (const float*)d_in[12];
    const float* mlp_w1     = (const float*)d_in[13];
    const float* mlp_b1     = (const float*)d_in[14];
    const float* mlp_w2     = (const float*)d_in[15];
    const float* mlp_b2     = (const float*)d_in[16];
    const float* bn_gamma   = (const float*)d_in[17];
    const float* bn_beta    = (const float*)d_in[18];
    const float* feat_w     = (const float*)d_in[19];
    const float* feat_b     = (const float*)d_in[20];
    const float* ol_w1      = (const float*)d_in[21];
    const float* ol_b1      = (const float*)d_in[22];
    const float* ol_w2      = (const float*)d_in[23];
    const float* ol_b2      = (const float*)d_in[24];
    (void)in_sizes; (void)n_in; (void)out_size; (void)ws_size;

    const int* srcp = edge_index;
    const int* dstp = edge_index + EE;

    char* ws = (char*)d_ws;
    size_t off_b = 0;
    auto alloc = [&](size_t bytes) -> char* {
        char* p = ws + off_b;
        off_b += (bytes + 255) & ~(size_t)255;
        return p;
    };
    float* H     = (float*)alloc((size_t)NN * DD * 4 + 256);
    float* AGG   = (float*)alloc((size_t)NN * DD * 4 + 256);
    int*   DEG   = (int*)  alloc((size_t)NN * 4);
    float* CNT   = (float*)alloc(GG * 4);
    float* HG    = (float*)alloc((size_t)GG * DD * 4);     // } pool 10,592,000 B
    float* HFEAT = (float*)alloc((size_t)GG * FEATN * 4);  // } packed W + CSR +
    float* TMP   = (float*)alloc((size_t)GG * FEATN * 4);  // } ETAB + REPS + SCL

    short* OLWP = (short*)HG;                        //   245,760 B
    short* W1P  = OLWP + (size_t)10 * 384 * 32;      // 2,048,000 B
    short* W2P  = W1P + (size_t)LL * 10 * 640 * 32;  // 2,334,720 B
    char*  csr  = (char*)(W2P + (size_t)LL * 19 * 384 * 32);
    int*   OFF  = (int*)csr;                         //   400,128
    int*   CURS = (int*)(csr + 400128);              //   400,128
    int*   EIDX = (int*)(csr + 800128);              //   800,128
    float* ETAB = (float*)(csr + 1600256);           //   150,000
    float* REPS = (float*)(csr + 1750272);           // 5*2*32*600*4 = 768,000
    float* SCL  = (float*)(csr + 2518528);           // 5*1200*4 = 24,000
    int*   BSUM = (int*)CNT;                         // end csr+2,542,528 <= pool

    float* outp = (float*)d_out;

    // allow dynamic LDS for k_mlp2 (60,672 B -> 2 blocks/CU)
    hipFuncSetAttribute((const void*)k_mlp2,
                        hipFuncAttributeMaxDynamicSharedMemorySize, MLP_LDS);

    // prepack weights (batched over grid.y) + combined edge tables
    k_pack<<<dim3(480, 1), 256, 0, stream>>>(out_lin_w, OLWP, 300, 300, 10, 384,
                                             0, 0);
    k_pack<<<dim3(800, LL), 256, 0, stream>>>(mlp_w1, W1P, DD, D2, 10, 640,
                                              (size_t)DD * D2, (size_t)10 * 640 * 32);
    k_pack<<<dim3(912, LL), 256, 0, stream>>>(mlp_w2, W2P, D2, DD, 19, 384,
                                              (size_t)D2 * DD, (size_t)19 * 384 * 32);
    k_etab<<<(LL * 25 * DD + 255) / 256, 256, 0, stream>>>(edge_emb, ETAB);
    hipMemsetAsync(REPS, 0, (size_t)LL * 2 * 32 * 600 * 4, stream);

    // CSR build
    hipMemsetAsync(DEG, 0, (size_t)NN * 4, stream);
    k_degree<<<(EE + 255) / 256, 256, 0, stream>>>(dstp, DEG);
    k_scan1<<<391, 256, 0, stream>>>(DEG, OFF, BSUM);
    k_scan2<<<1, 512, 0, stream>>>(BSUM, OFF, 391);
    k_scan3<<<391, 256, 0, stream>>>(OFF, BSUM, CURS);
    k_fill<<<(EE + 255) / 256, 256, 0, stream>>>(dstp, CURS, EIDX);

    // node init (QB aliases AGG)
    short* QB = (short*)AGG;
    k_embed<<<(NN + 3) / 4, 256, 0, stream>>>(x, atom_emb, att_vec, QB);
    k_g1<<<NN / 32, 256, 0, stream>>>(QB, OLWP, out_lin_b, H);
    k_gaussg<<<(NN + 3) / 4, 320, 0, stream>>>(OFF, EIDX, edge_dist, g_means,
                                               g_stds, scale_p, H);
    k_repack<<<(EE + 255) / 256, 256, 0, stream>>>(EIDX, srcp, edge_attr);

    // layer loop: P stored bf16 (aliases H buffer) for l<4, fp32 H for l=4
    for (int l = 0; l < LL; l++) {
        const float* sc = SCL + (size_t)(l - 1) * 1200;   // valid only l>0
        k_agg<<<(NN + 7) / 8, 512, 0, stream>>>(
            (const void*)H, OFF, EIDX, ETAB + (size_t)l * 25 * DD,
            l > 0 ? sc : SCL, l > 0 ? sc + 600 : SCL, l > 0 ? 1 : 0, QB);
        k_mlp2<<<(NN + RPB - 1) / RPB, 512, MLP_LDS, stream>>>(
            QB, W1P + (size_t)l * 10 * 640 * 32, mlp_b1 + (size_t)l * D2,
            W2P + (size_t)l * 19 * 384 * 32, mlp_b2 + (size_t)l * DD,
            (void*)H, (l < LL - 1) ? 1 : 0,
            REPS + (size_t)l * 38400);
        k_bnprep<<<2, 256, 0, stream>>>(REPS + (size_t)l * 38400,
                                        SCL + (size_t)l * 1200,
                                        bn_gamma + (size_t)l * DD,
                                        bn_beta + (size_t)l * DD);
    }

    // pooling (count fused into k_pool); last BN folded into k_hgdiv
    hipMemsetAsync(CNT, 0, (size_t)GG * 4, stream);
    hipMemsetAsync(HG, 0, (size_t)GG * DD * 4, stream);
    k_pool<<<(NN + ROWS_PER - 1) / ROWS_PER, 320, 0, stream>>>(H, batch, HG, CNT);
    k_hgdiv<<<(GG * DD + 255) / 256, 256, 0, stream>>>(HG, CNT,
                                                       SCL + (size_t)4 * 1200);
    {
        dim3 grid((FEATN + 63) / 64, (GG + 15) / 16);
        k_gemm<<<grid, 256, 0, stream>>>(HG, feat_w, feat_b, HFEAT, outp,
                                         GG, DD, FEATN, 0);
    }
    {
        dim3 grid((FEATN + 63) / 64, (GG + 15) / 16);
        k_gemm<<<grid, 256, 0, stream>>>(HFEAT, ol_w1, ol_b1, TMP, nullptr,
                                         GG, FEATN, FEATN, 1);
    }
    {
        dim3 grid((OUT2 + 63) / 64, (GG + 15) / 16);
        k_gemm<<<grid, 256, 0, stream>>>(TMP, ol_w2, ol_b2, nullptr,
                                         outp + (size_t)GG * FEATN,
                                         GG, FEATN, OUT2, 0);
    }
}

// Round 14
// 1649.617 us; speedup vs baseline: 1.1029x; 1.1029x over previous
//
#include <hip/hip_runtime.h>
#include <hip/hip_bf16.h>

// GINet forward, fp32 in/out. R28 = R26 revert (1655us best) + 16B P-copy.
// R27's wave-per-node k_agg REGRESSED +164us (doubled per-thread column
// state + 11/64-lane B-loads outweighed the ~0.35-iter divergence saving) —
// third failed k_agg restructure; the 4-node/80-thr/2-edge-batch version is
// a verified local optimum and is now frozen, like k_mlp2 (reg-walled) and
// the head gemms. Only change vs R26: k_mlp2's staged LDS->global P copy
// uses vec8s (16B) stores (panel sizes divisible by 8; bases 16B-aligned).

#define NN   100000
#define EE   200000
#define GG   2000
#define DD   300
#define D2   600
#define LL   5
#define FEATN 512
#define OUT2 256
#define ROWS_PER 256
#define RPB  48          // rows per k_mlp2 block
#define MLP_LDS (RPB * 632 * 2)   // 60,672 B -> 2 blocks/CU

typedef __hip_bfloat16 bf16;
typedef short vec8s __attribute__((ext_vector_type(8)));
typedef short vec4s __attribute__((ext_vector_type(4)));
typedef float vec4f __attribute__((ext_vector_type(4)));

__device__ __forceinline__ short f2bs(float v) {
    bf16 h = __float2bfloat16(v);
    return __builtin_bit_cast(short, h);
}
__device__ __forceinline__ float bs2f(short s) {
    unsigned u = ((unsigned)(unsigned short)s) << 16;
    return __builtin_bit_cast(float, u);
}

// ---- weight prepack: src[K][N] fp32 -> dst[kt][col<NPAD][32] bf16 ----
// batched over blockIdx.y (layer); strides in elements
__global__ void k_pack(const float* __restrict__ src0, short* __restrict__ dst0,
                       int Ksrc, int Nsrc, int KT, int NPAD,
                       size_t sstride, size_t dstride)
{
    const float* src = src0 + (size_t)blockIdx.y * sstride;
    short* dst = dst0 + (size_t)blockIdx.y * dstride;
    int idx = blockIdx.x * 256 + threadIdx.x;
    int total = KT * NPAD * 32;
    if (idx >= total) return;
    int col = idx % NPAD;
    int tmp = idx / NPAD;
    int kk  = tmp % 32;
    int kt  = tmp / 32;
    int k = kt * 32 + kk;
    short v = 0;
    if (k < Ksrc && col < Nsrc) v = f2bs(src[(size_t)k * Nsrc + col]);
    dst[((size_t)kt * NPAD + col) * 32 + kk] = v;
}

// ---- combined edge-emb tables: E[l][c][d], c<24 = a0*6+a1*2+a2, c==24 self ----
__global__ void k_etab(const float* __restrict__ edge_emb, float* __restrict__ E)
{
    int i = blockIdx.x * 256 + threadIdx.x;
    if (i >= LL * 25 * DD) return;
    int d = i % DD;
    int t = i / DD;
    int c = t % 25;
    int l = t / 25;
    int a0 = (c == 24) ? 4 : (c / 6);
    int a1 = (c == 24) ? 0 : ((c % 6) / 2);
    int a2 = (c == 24) ? 0 : (c % 2);
    const float* e0 = edge_emb + (size_t)((l * 3 + 0) * 5) * DD;
    const float* e1 = edge_emb + (size_t)((l * 3 + 1) * 5) * DD;
    const float* e2 = edge_emb + (size_t)((l * 3 + 2) * 5) * DD;
    E[i] = e0[a0 * DD + d] + e1[a1 * DD + d] + e2[a2 * DD + d];
}

// ---- repack EIDX: edge id -> src | (combo<<17) ----
__global__ void k_repack(int* __restrict__ eidx, const int* __restrict__ src,
                         const int* __restrict__ attr)
{
    int i = blockIdx.x * 256 + threadIdx.x;
    if (i >= EE) return;
    int e = eidx[i];
    int c = attr[e * 3] * 6 + attr[e * 3 + 1] * 2 + attr[e * 3 + 2];
    eidx[i] = src[e] | (c << 17);
}

// ---- fused MLP layer + replicated BN stats; 48 rows/block, 8 waves ----
__global__ __launch_bounds__(512, 4) void k_mlp2(
    const short* __restrict__ Qb, const short* __restrict__ W1P,
    const float* __restrict__ b1, const short* __restrict__ W2P,
    const float* __restrict__ b2, void* __restrict__ Pout, int f16out,
    float* __restrict__ RS)            // [2][32][600] partial sums for layer
{
    extern __shared__ __align__(16) char smem_c[];
    short* Apan = (short*)smem_c;                 // 48 rows x 320 shorts, swizzled
    short (*Hl)[632] = (short(*)[632])smem_c;     // overlaps Apan (A dead first)

    const int t = threadIdx.x;
    const int wv = t >> 6, lane = t & 63;
    const int m = lane & 15, quad = lane >> 4;
    const int rb = (int)blockIdx.x * RPB;
    const int rep = ((int)blockIdx.x & 31) * 600;

    // ---- stage A-panel: global_load_lds, source-swizzled (chunk ^= row&7) ----
    {
        const short* qbase = Qb + (size_t)rb * 320;
#pragma unroll
        for (int i = 0; i < 4; i++) {
            int j = i * 8 + wv;                       // 1KB issue index, j < 30
            if (j < 30) {
                int c   = j * 64 + lane;              // 16B chunk index
                int c8  = c >> 3;
                int row = c8 / 5;
                int ch  = (c8 - row * 5) * 8 + (lane & 7);
                const short* src = qbase + (size_t)row * 320
                                 + (size_t)((ch ^ (row & 7)) * 8);
                __builtin_amdgcn_global_load_lds(
                    (const __attribute__((address_space(1))) unsigned int*)src,
                    (__attribute__((address_space(3))) unsigned int*)(smem_c + j * 1024),
                    16, 0, 0);
            }
        }
    }

    // per-lane swizzled A-read bases (shorts): parity-split on eh = (m>>2)&1
    const int ql   = quad ^ (m & 3);
    const int eh   = (m >> 2) & 1;
    const int abE  = m * 320 + ql * 8 + eh * 32;        // even kt base
    const int abO  = m * 320 + ql * 8 + (1 - eh) * 32;  // odd kt base

    vec4f acc1[3][5];
#pragma unroll
    for (int g = 0; g < 3; g++)
#pragma unroll
        for (int cf = 0; cf < 5; cf++) acc1[g][cf] = (vec4f)0.f;

    // ---- stage 1: Hl = relu(Qb @ W1 + b1), operand-swapped MFMA ----
    const short* w1b = W1P + ((size_t)(wv * 80 + m) * 32) + quad * 8;
    vec8s bcur[5], bnxt[5];
#pragma unroll
    for (int cf = 0; cf < 5; cf++) bcur[cf] = *(const vec8s*)(w1b + cf * 512);

    __syncthreads();   // A-panel DMA drained (vmcnt0 at barrier)

#pragma unroll
    for (int kt = 0; kt < 10; kt++) {
        if (kt < 9) {
            const short* wn = w1b + (size_t)(kt + 1) * 20480;
#pragma unroll
            for (int cf = 0; cf < 5; cf++) bnxt[cf] = *(const vec8s*)(wn + cf * 512);
        }
        const int base = (kt & 1) ? abO : abE;
        const int koff = (kt & ~1) * 32;
        vec8s af[3];
#pragma unroll
        for (int g = 0; g < 3; g++)
            af[g] = *(const vec8s*)(Apan + base + koff + g * 5120);
        __builtin_amdgcn_s_setprio(1);
#pragma unroll
        for (int cf = 0; cf < 5; cf++)
#pragma unroll
            for (int g = 0; g < 3; g++)
                acc1[g][cf] = __builtin_amdgcn_mfma_f32_16x16x32_bf16(
                    bcur[cf], af[g], acc1[g][cf], 0, 0, 0);
        __builtin_amdgcn_s_setprio(0);
#pragma unroll
        for (int cf = 0; cf < 5; cf++) bcur[cf] = bnxt[cf];
    }

    // prefetch stage-2 B tiles 0 and 1 (global, independent of LDS)
    const short* w2b = W2P + ((size_t)(wv * 48 + m) * 32) + quad * 8;
    vec8s b2f[2][3];
#pragma unroll
    for (int cf = 0; cf < 3; cf++) {
        b2f[0][cf] = *(const vec8s*)(w2b + cf * 512);
        b2f[1][cf] = *(const vec8s*)(w2b + 12288 + cf * 512);
    }

    __syncthreads();   // all A-panel reads done before Hl overwrites region

    // stage-1 epilogue: bias+relu+bf16; lane holds 4 consecutive cols of a row
#pragma unroll
    for (int g = 0; g < 3; g++) {
#pragma unroll
        for (int cf = 0; cf < 5; cf++) {
            const int col0 = wv * 80 + cf * 16 + quad * 4;
            if (col0 < 600) {
                vec4f bv = *(const vec4f*)(b1 + col0);
                vec4s o;
#pragma unroll
                for (int r = 0; r < 4; r++)
                    o[r] = f2bs(fmaxf(acc1[g][cf][r] + bv[r], 0.f));
                *(vec4s*)&Hl[g * 16 + m][col0] = o;
            } else if (col0 < 608) {
                *(vec4s*)&Hl[g * 16 + m][col0] = (vec4s)0;
            }
        }
    }
    __syncthreads();

    // ---- stage 2 + stats into replica; staged coalesced P write ----
    {
        vec4f acc2[3][3];
#pragma unroll
        for (int g = 0; g < 3; g++)
#pragma unroll
            for (int cf = 0; cf < 3; cf++) acc2[g][cf] = (vec4f)0.f;

#pragma unroll
        for (int kt = 0; kt < 19; kt++) {
            vec8s ha[3];
#pragma unroll
            for (int g = 0; g < 3; g++)
                ha[g] = *(const vec8s*)&Hl[g * 16 + m][kt * 32 + quad * 8];
            __builtin_amdgcn_s_setprio(1);
#pragma unroll
            for (int cf = 0; cf < 3; cf++)
#pragma unroll
                for (int g = 0; g < 3; g++)
                    acc2[g][cf] = __builtin_amdgcn_mfma_f32_16x16x32_bf16(
                        ha[g], b2f[kt & 1][cf], acc2[g][cf], 0, 0, 0);
            __builtin_amdgcn_s_setprio(0);
            if (kt < 17) {
                const short* wn = w2b + (size_t)(kt + 2) * 12288;
#pragma unroll
                for (int cf = 0; cf < 3; cf++)
                    b2f[kt & 1][cf] = *(const vec8s*)(wn + cf * 512);
            }
        }

        __syncthreads();   // Hl reads complete; region reused for staged P

        short* Ps  = (short*)smem_c;   // [48][300] bf16 (28.8KB)
        float* Pw  = (float*)smem_c;   // [48][300] fp32 (57.6KB <= 60.6KB)

#pragma unroll
        for (int cf = 0; cf < 3; cf++) {
            int gc = wv * 48 + cf * 16 + m;
            bool ok = (gc < DD);
            float bv = ok ? b2[gc] : 0.f;
            float s = 0.f, q = 0.f;
#pragma unroll
            for (int g = 0; g < 3; g++) {
#pragma unroll
                for (int reg = 0; reg < 4; reg++) {
                    int rl = g * 16 + quad * 4 + reg;
                    bool vr = (rb + rl) < NN;
                    float v = acc2[g][cf][reg] + bv;
                    if (ok) {
                        if (f16out) Ps[rl * 300 + gc] = f2bs(v);
                        else        Pw[rl * 300 + gc] = v;
                    }
                    if (vr) { s += v; q += v * v; }
                }
            }
            s += __shfl_xor(s, 16); s += __shfl_xor(s, 32);
            q += __shfl_xor(q, 16); q += __shfl_xor(q, 32);
            if (ok && quad == 0) {
                atomicAdd(&RS[rep + gc], s);
                atomicAdd(&RS[19200 + rep + gc], q);
            }
        }
        __syncthreads();

        // coalesced linear copy LDS -> Pout (block's rows are contiguous)
        int nrows = NN - rb; if (nrows > RPB) nrows = RPB;
        if (f16out) {
            int total8 = nrows * 300 / 8;
            short* dst = (short*)Pout + (size_t)rb * 300;
            for (int i = t; i < total8; i += 512)
                *(vec8s*)(dst + i * 8) = *(const vec8s*)(Ps + i * 8);
        } else {
            int total4 = nrows * 300 / 4;
            float* dst = (float*)Pout + (size_t)rb * 300;
            for (int i = t; i < total4; i += 512)
                *(vec4f*)(dst + i * 4) = *(const vec4f*)(Pw + i * 4);
        }
    }
}

// ---- embed GEMM, stage1 shape with A+B double-buffer: H = Qb @ OLWP + b ----
__global__ __launch_bounds__(256) void k_g1(
    const short* __restrict__ Qb, const short* __restrict__ WP,
    const float* __restrict__ bias, float* __restrict__ H)
{
    const int t = threadIdx.x;
    const int wv = t >> 6, lane = t & 63;
    const int m = lane & 15, quad = lane >> 4;
    const int rb = (int)blockIdx.x * 32;
    const short* arow0 = Qb + (size_t)(rb + m) * 320 + quad * 8;
    const short* arow1 = arow0 + (size_t)16 * 320;
    const short* wb0 = WP + ((size_t)(wv * 80 + m) * 32) + quad * 8;

    vec4f acc[2][5];
#pragma unroll
    for (int g = 0; g < 2; g++)
#pragma unroll
        for (int cf = 0; cf < 5; cf++) acc[g][cf] = (vec4f)0.f;

    vec8s af0 = *(const vec8s*)arow0;
    vec8s af1 = *(const vec8s*)arow1;
    vec8s bcur[5], bnxt[5];
#pragma unroll
    for (int cf = 0; cf < 5; cf++) bcur[cf] = *(const vec8s*)(wb0 + cf * 512);

#pragma unroll
    for (int kt = 0; kt < 10; kt++) {
        vec8s an0 = af0, an1 = af1;
        if (kt < 9) {
            an0 = *(const vec8s*)(arow0 + (kt + 1) * 32);
            an1 = *(const vec8s*)(arow1 + (kt + 1) * 32);
            const short* wn = wb0 + (size_t)(kt + 1) * 12288;
#pragma unroll
            for (int cf = 0; cf < 5; cf++) bnxt[cf] = *(const vec8s*)(wn + cf * 512);
        }
#pragma unroll
        for (int cf = 0; cf < 5; cf++) {
            acc[0][cf] = __builtin_amdgcn_mfma_f32_16x16x32_bf16(af0, bcur[cf], acc[0][cf], 0, 0, 0);
            acc[1][cf] = __builtin_amdgcn_mfma_f32_16x16x32_bf16(af1, bcur[cf], acc[1][cf], 0, 0, 0);
        }
        af0 = an0; af1 = an1;
#pragma unroll
        for (int cf = 0; cf < 5; cf++) bcur[cf] = bnxt[cf];
    }
#pragma unroll
    for (int cf = 0; cf < 5; cf++) {
        int gc = wv * 80 + cf * 16 + m;
        if (gc >= DD) continue;
        float bv = bias[gc];
#pragma unroll
        for (int g = 0; g < 2; g++)
#pragma unroll
            for (int reg = 0; reg < 4; reg++)
                H[(size_t)(rb + g * 16 + quad * 4 + reg) * DD + gc] = acc[g][cf][reg] + bv;
    }
}

// ============ CSR build ============
__global__ void k_degree(const int* __restrict__ dst, int* __restrict__ deg) {
    int e = blockIdx.x * 256 + threadIdx.x;
    if (e < EE) atomicAdd(&deg[dst[e]], 1);
}

__global__ void k_scan1(const int* __restrict__ deg, int* __restrict__ off,
                        int* __restrict__ bsum)
{
    __shared__ int s[256];
    int i = blockIdx.x * 256 + threadIdx.x;
    int v = (i < NN) ? deg[i] : 0;
    s[threadIdx.x] = v;
    __syncthreads();
    for (int o = 1; o < 256; o <<= 1) {
        int tv = (threadIdx.x >= o) ? s[threadIdx.x - o] : 0;
        __syncthreads();
        s[threadIdx.x] += tv;
        __syncthreads();
    }
    if (i < NN) off[i] = s[threadIdx.x] - v;
    if (threadIdx.x == 255) bsum[blockIdx.x] = s[255];
}

// parallel scan over nb (<512) block sums: one 512-thread block
__global__ void k_scan2(int* __restrict__ bsum, int* __restrict__ off, int nb) {
    __shared__ int ws[8];
    int t = threadIdx.x;
    int v = (t < nb) ? bsum[t] : 0;
    int s = v;
    for (int o = 1; o < 64; o <<= 1) {
        int u = __shfl_up(s, o, 64);
        if ((t & 63) >= o) s += u;
    }
    if ((t & 63) == 63) ws[t >> 6] = s;
    __syncthreads();
    if (t < 8) {
        int a = ws[t];
        for (int o = 1; o < 8; o <<= 1) {
            int u = __shfl_up(a, o, 64);
            if (t >= o) a += u;
        }
        ws[t] = a;
    }
    __syncthreads();
    int base = (t >> 6) ? ws[(t >> 6) - 1] : 0;
    int incl = s + base;
    if (t < nb) bsum[t] = incl - v;      // exclusive
    if (t == nb - 1) off[NN] = incl;     // total
}

__global__ void k_scan3(int* __restrict__ off, const int* __restrict__ bsum,
                        int* __restrict__ curs)
{
    int i = blockIdx.x * 256 + threadIdx.x;
    if (i >= NN) return;
    int v = off[i] + bsum[i >> 8];
    off[i] = v;
    curs[i] = v;
}

__global__ void k_fill(const int* __restrict__ dst, int* __restrict__ curs,
                       int* __restrict__ eidx)
{
    int e = blockIdx.x * 256 + threadIdx.x;
    if (e >= EE) return;
    int pos = atomicAdd(&curs[dst[e]], 1);
    eidx[pos] = e;
}

// ============ embed attention -> bf16 rows (stride 320, pads zeroed) ============
__global__ __launch_bounds__(256) void k_embed(
    const int* __restrict__ x, const float* __restrict__ atom_emb,
    const float* __restrict__ att_vec, short* __restrict__ fusedb)
{
    int wave = threadIdx.x >> 6;
    int lane = threadIdx.x & 63;
    int n = blockIdx.x * 4 + wave;
    if (n >= NN) return;

    float att[5];
#pragma unroll
    for (int j = 0; j < 5; j++) {
        int d = lane + 64 * j;
        att[j] = (d < DD) ? att_vec[d] : 0.f;
    }
    float emb[9][5];
    float sc[9];
#pragma unroll
    for (int f = 0; f < 9; f++) {
        int idx = x[n * 9 + f];
        const float* p = atom_emb + (size_t)(f * 119 + idx) * DD;
        float partial = 0.f;
#pragma unroll
        for (int j = 0; j < 5; j++) {
            int d = lane + 64 * j;
            float v = (d < DD) ? p[d] : 0.f;
            emb[f][j] = v;
            partial += v * att[j];
        }
#pragma unroll
        for (int off = 32; off; off >>= 1) partial += __shfl_xor(partial, off, 64);
        sc[f] = partial;
    }
    float mx = sc[0];
#pragma unroll
    for (int f = 1; f < 9; f++) mx = fmaxf(mx, sc[f]);
    float s = 0.f;
#pragma unroll
    for (int f = 0; f < 9; f++) { sc[f] = __expf(sc[f] - mx); s += sc[f]; }
    float inv = 1.f / s;
#pragma unroll
    for (int j = 0; j < 5; j++) {
        int d = lane + 64 * j;
        float acc = 0.f;
        if (d < DD) {
#pragma unroll
            for (int f = 0; f < 9; f++) acc += emb[f][j] * sc[f];
            acc *= inv;
        }
        fusedb[(size_t)n * 320 + d] = (d < DD) ? f2bs(acc) : (short)0;
    }
}

// ---- gaussian basis: 4 nodes/block x 80 thr, d4 grain ----
__global__ __launch_bounds__(320) void k_gaussg(
    const int* __restrict__ off, const int* __restrict__ eidx,
    const float* __restrict__ dist, const float* __restrict__ g_means,
    const float* __restrict__ g_stds, const float* __restrict__ scale_p,
    float* __restrict__ H)
{
    int tn = threadIdx.x / 80;
    int td = threadIdx.x - tn * 80;
    int n = blockIdx.x * 4 + tn;
    if (n >= NN) return;
    int d4 = td * 4;
    if (d4 >= DD) return;
    int beg = off[n], end = off[n + 1];
    if (beg == end) return;
    vec4f gs = *(const vec4f*)(g_stds + d4);
    vec4f gm = *(const vec4f*)(g_means + d4);
    float sd[4], mean[4], inva[4], sum[4];
#pragma unroll
    for (int j = 0; j < 4; j++) {
        sd[j] = fabsf(gs[j]) + 0.01f;
        mean[j] = gm[j];
        inva[j] = 1.f / (2.5066263f * sd[j]);
        sum[j] = 0.f;
    }
    for (int i = beg; i < end; i++) {
        float xv = dist[eidx[i]];
#pragma unroll
        for (int j = 0; j < 4; j++) {
            float z = (xv - mean[j]) / sd[j];
            sum[j] += __expf(-0.5f * z * z) * inva[j];
        }
    }
    int deg = end - beg;
    int c = deg - 1; c = c < 0 ? 0 : (c > 3 ? 3 : c);
    vec4f sp = *(const vec4f*)(scale_p + c * DD + d4);
    float* hp = H + (size_t)n * DD + d4;
    vec4f hv = *(const vec4f*)hp;
#pragma unroll
    for (int j = 0; j < 4; j++) hv[j] += __expf(sp[j]) * sum[j];
    *(vec4f*)hp = hv;
}

// ---- fused aggregation: 4 nodes/block x 80 thr, short4 grain, 2-edge
//      batched gather issue. apply=0: fp32 P, apply=1: bf16 P ----
__global__ __launch_bounds__(320) void k_agg(
    const void* __restrict__ P, const int* __restrict__ off,
    const int* __restrict__ eidxp, const float* __restrict__ E,
    const float* __restrict__ scale, const float* __restrict__ shift,
    int apply, short* __restrict__ Qb)
{
    int tn = threadIdx.x / 80;
    int td = threadIdx.x - tn * 80;
    int n = blockIdx.x * 4 + tn;
    if (n >= NN) return;
    int d4 = td * 4;
    if (d4 >= DD) {   // cols 300..316 -> zero pads (covers 300..319)
        *(vec4s*)&Qb[(size_t)n * 320 + d4] = (vec4s)0;
        return;
    }
    const float* Pf = (const float*)P;
    const short* Ph = (const short*)P;

    float a[4];
    float sc[4], sh[4];
    if (apply) {
        vec4f s4 = *(const vec4f*)(scale + d4);
        vec4f h4 = *(const vec4f*)(shift + d4);
#pragma unroll
        for (int j = 0; j < 4; j++) { sc[j] = s4[j]; sh[j] = h4[j]; }
        vec4s pv = *(const vec4s*)(Ph + (size_t)n * 300 + d4);
#pragma unroll
        for (int j = 0; j < 4; j++)
            a[j] = fmaxf(bs2f(pv[j]) * sc[j] + sh[j], 0.f);
    } else {
        vec4f self = *(const vec4f*)(Pf + (size_t)n * DD + d4);
#pragma unroll
        for (int j = 0; j < 4; j++) a[j] = self[j];
    }
    {
        vec4f es = *(const vec4f*)(E + 24 * DD + d4);
#pragma unroll
        for (int j = 0; j < 4; j++) a[j] += es[j];
    }

    int beg = off[n], end = off[n + 1];
    int i = beg;
    if (apply) {
        for (; i + 1 < end; i += 2) {
            int v0 = eidxp[i], v1 = eidxp[i + 1];
            int s0 = v0 & 131071, c0 = v0 >> 17;
            int s1 = v1 & 131071, c1 = v1 >> 17;
            vec4s p0 = *(const vec4s*)(Ph + (size_t)s0 * 300 + d4);
            vec4s p1 = *(const vec4s*)(Ph + (size_t)s1 * 300 + d4);
            vec4f e0 = *(const vec4f*)(E + c0 * DD + d4);
            vec4f e1 = *(const vec4f*)(E + c1 * DD + d4);
#pragma unroll
            for (int j = 0; j < 4; j++)
                a[j] += fmaxf(bs2f(p0[j]) * sc[j] + sh[j], 0.f) + e0[j];
#pragma unroll
            for (int j = 0; j < 4; j++)
                a[j] += fmaxf(bs2f(p1[j]) * sc[j] + sh[j], 0.f) + e1[j];
        }
        if (i < end) {
            int v0 = eidxp[i];
            int s0 = v0 & 131071, c0 = v0 >> 17;
            vec4s p0 = *(const vec4s*)(Ph + (size_t)s0 * 300 + d4);
            vec4f e0 = *(const vec4f*)(E + c0 * DD + d4);
#pragma unroll
            for (int j = 0; j < 4; j++)
                a[j] += fmaxf(bs2f(p0[j]) * sc[j] + sh[j], 0.f) + e0[j];
        }
    } else {
        for (; i + 1 < end; i += 2) {
            int v0 = eidxp[i], v1 = eidxp[i + 1];
            int s0 = v0 & 131071, c0 = v0 >> 17;
            int s1 = v1 & 131071, c1 = v1 >> 17;
            vec4f p0 = *(const vec4f*)(Pf + (size_t)s0 * DD + d4);
            vec4f p1 = *(const vec4f*)(Pf + (size_t)s1 * DD + d4);
            vec4f e0 = *(const vec4f*)(E + c0 * DD + d4);
            vec4f e1 = *(const vec4f*)(E + c1 * DD + d4);
#pragma unroll
            for (int j = 0; j < 4; j++) a[j] += p0[j] + e0[j];
#pragma unroll
            for (int j = 0; j < 4; j++) a[j] += p1[j] + e1[j];
        }
        if (i < end) {
            int v0 = eidxp[i];
            int s0 = v0 & 131071, c0 = v0 >> 17;
            vec4f p0 = *(const vec4f*)(Pf + (size_t)s0 * DD + d4);
            vec4f e0 = *(const vec4f*)(E + c0 * DD + d4);
#pragma unroll
            for (int j = 0; j < 4; j++) a[j] += p0[j] + e0[j];
        }
    }
    vec4s o;
#pragma unroll
    for (int j = 0; j < 4; j++) o[j] = f2bs(a[j]);
    *(vec4s*)&Qb[(size_t)n * 320 + d4] = o;
}

// ---- reduce 32 replicas -> scale/shift for the layer ----
__global__ void k_bnprep(const float* __restrict__ RS, float* __restrict__ SC,
                         const float* __restrict__ gamma,
                         const float* __restrict__ beta)
{
    int d = threadIdx.x + blockIdx.x * 256;
    if (d >= DD) return;
    float s = 0.f, q = 0.f;
    for (int r = 0; r < 32; r++) {
        s += RS[r * 600 + d];
        q += RS[19200 + r * 600 + d];
    }
    float mu = s * (1.f / NN);
    float var = q * (1.f / NN) - mu * mu;
    var = fmaxf(var, 0.f);
    float sc = gamma[d] * rsqrtf(var + 1e-5f);
    SC[d] = sc;
    SC[600 + d] = beta[d] - mu * sc;
}

// ============ pooling (with fused run-length counting) + head ============
__global__ __launch_bounds__(320) void k_pool(const float* __restrict__ H,
                                              const int* __restrict__ batch,
                                              float* __restrict__ HG,
                                              float* __restrict__ cnt)
{
    __shared__ int sb[ROWS_PER];
    int r0 = blockIdx.x * ROWS_PER;
    int rend = min(r0 + ROWS_PER, NN);
    for (int i = threadIdx.x; i < rend - r0; i += 320) sb[i] = batch[r0 + i];
    __syncthreads();
    int d = threadIdx.x;
    if (d >= DD) return;
    int cur = sb[0];
    float acc = 0.f;
    int run = 0;
    for (int r = r0; r < rend; r++) {
        int b = sb[r - r0];
        if (b != cur) {
            atomicAdd(&HG[(size_t)cur * DD + d], acc);
            if (d == 0) atomicAdd(&cnt[cur], (float)run);
            acc = 0.f; run = 0; cur = b;
        }
        acc += H[(size_t)r * DD + d];
        run++;
    }
    atomicAdd(&HG[(size_t)cur * DD + d], acc);
    if (d == 0) atomicAdd(&cnt[cur], (float)run);
}

__global__ void k_hgdiv(float* __restrict__ HG, const float* __restrict__ cnt,
                        const float* __restrict__ SC)
{
    int idx = blockIdx.x * 256 + threadIdx.x;
    if (idx >= GG * DD) return;
    int d = idx % DD;
    float mean = HG[idx] / fmaxf(cnt[idx / DD], 1.0f);
    HG[idx] = mean * SC[d] + SC[600 + d];
}

// ---- head GEMM: 16x64 tile, 1x4 outputs/thread, high occupancy ----
__global__ __launch_bounds__(256) void k_gemm(
    const float* __restrict__ A, const float* __restrict__ W,
    const float* __restrict__ bias, float* __restrict__ Cf,
    float* __restrict__ Cout, int M, int K, int Ncol, int relu)
{
    __shared__ float Ash[16][33];
    const int tx = threadIdx.x & 15;        // col group (float4)
    const int ty = threadIdx.x >> 4;        // row 0..15
    const int rb = blockIdx.y * 16;
    const int col = blockIdx.x * 64 + tx * 4;

    float acc[4] = {0.f, 0.f, 0.f, 0.f};

    for (int k0 = 0; k0 < K; k0 += 32) {
        // stage A[rb..rb+16)[k0..k0+32) -> Ash (256 thr x 2 floats)
        {
            int r  = threadIdx.x >> 4;
            int kk = (threadIdx.x & 15) * 2;
            int row = rb + r;
            float vx = 0.f, vy = 0.f;
            if (row < M) {
                const float* ap = A + (size_t)row * K + k0 + kk;
                if (k0 + kk + 1 < K) {
                    float2 v = *(const float2*)ap;
                    vx = v.x; vy = v.y;
                } else if (k0 + kk < K) {
                    vx = ap[0];
                }
            }
            Ash[r][kk]     = vx;
            Ash[r][kk + 1] = vy;
        }
        __syncthreads();

        const int kmax = (K - k0 < 32) ? (K - k0) : 32;
        const float* wp = W + (size_t)k0 * Ncol + col;
#pragma unroll 4
        for (int k = 0; k < kmax; k++) {
            float4 wv = *(const float4*)(wp + (size_t)k * Ncol);
            float a = Ash[ty][k];
            acc[0] += a * wv.x; acc[1] += a * wv.y;
            acc[2] += a * wv.z; acc[3] += a * wv.w;
        }
        __syncthreads();
    }

    int row = rb + ty;
    if (row < M) {
        float4 bv = *(const float4*)(bias + col);
        float4 o;
        o.x = acc[0] + bv.x; o.y = acc[1] + bv.y;
        o.z = acc[2] + bv.z; o.w = acc[3] + bv.w;
        if (relu) {
            o.x = fmaxf(o.x, 0.f); o.y = fmaxf(o.y, 0.f);
            o.z = fmaxf(o.z, 0.f); o.w = fmaxf(o.w, 0.f);
        }
        if (Cf)   *(float4*)(Cf   + (size_t)row * Ncol + col) = o;
        if (Cout) *(float4*)(Cout + (size_t)row * Ncol + col) = o;
    }
}

extern "C" void kernel_launch(void* const* d_in, const int* in_sizes, int n_in,
                              void* d_out, int out_size, void* d_ws, size_t ws_size,
                              hipStream_t stream)
{
    const int*   x          = (const int*)  d_in[0];
    const int*   edge_index = (const int*)  d_in[1];
    const int*   edge_attr  = (const int*)  d_in[2];
    const float* edge_dist  = (const float*)d_in[3];
    const int*   batch      = (const int*)  d_in[4];
    const float* atom_emb   = (const float*)d_in[5];
    const float* att_vec    = (const float*)d_in[6];
    const float* out_lin_w  = (const float*)d_in[7];
    const float* out_lin_b  = (const float*)d_in[8];
    const float* g_means    = (const float*)d_in[9];
    const float* g_stds     = (const float*)d_in[10];
    const float* scale_p    = (const float*)d_in[11];
    const float* edge_emb   = (const float*)d_in[12];
    const float* mlp_w1     = (const float*)d_in[13];
    const float* mlp_b1     = (const float*)d_in[14];
    const float* mlp_w2     = (const float*)d_in[15];
    const float* mlp_b2     = (const float*)d_in[16];
    const float* bn_gamma   = (const float*)d_in[17];
    const float* bn_beta    = (const float*)d_in[18];
    const float* feat_w     = (const float*)d_in[19];
    const float* feat_b     = (const float*)d_in[20];
    const float* ol_w1      = (const float*)d_in[21];
    const float* ol_b1      = (const float*)d_in[22];
    const float* ol_w2      = (const float*)d_in[23];
    const float* ol_b2      = (const float*)d_in[24];
    (void)in_sizes; (void)n_in; (void)out_size; (void)ws_size;

    const int* srcp = edge_index;
    const int* dstp = edge_index + EE;

    char* ws = (char*)d_ws;
    size_t off_b = 0;
    auto alloc = [&](size_t bytes) -> char* {
        char* p = ws + off_b;
        off_b += (bytes + 255) & ~(size_t)255;
        return p;
    };
    float* H     = (float*)alloc((size_t)NN * DD * 4 + 256);
    float* AGG   = (float*)alloc((size_t)NN * DD * 4 + 256);
    int*   DEG   = (int*)  alloc((size_t)NN * 4);
    float* CNT   = (float*)alloc(GG * 4);
    float* HG    = (float*)alloc((size_t)GG * DD * 4);     // } pool 10,592,000 B
    float* HFEAT = (float*)alloc((size_t)GG * FEATN * 4);  // } packed W + CSR +
    float* TMP   = (float*)alloc((size_t)GG * FEATN * 4);  // } ETAB + REPS + SCL

    short* OLWP = (short*)HG;                        //   245,760 B
    short* W1P  = OLWP + (size_t)10 * 384 * 32;      // 2,048,000 B
    short* W2P  = W1P + (size_t)LL * 10 * 640 * 32;  // 2,334,720 B
    char*  csr  = (char*)(W2P + (size_t)LL * 19 * 384 * 32);
    int*   OFF  = (int*)csr;                         //   400,128
    int*   CURS = (int*)(csr + 400128);              //   400,128
    int*   EIDX = (int*)(csr + 800128);              //   800,128
    float* ETAB = (float*)(csr + 1600256);           //   150,000
    float* REPS = (float*)(csr + 1750272);           // 5*2*32*600*4 = 768,000
    float* SCL  = (float*)(csr + 2518528);           // 5*1200*4 = 24,000
    int*   BSUM = (int*)CNT;                         // end csr+2,542,528 <= pool

    float* outp = (float*)d_out;

    // allow dynamic LDS for k_mlp2 (60,672 B -> 2 blocks/CU)
    hipFuncSetAttribute((const void*)k_mlp2,
                        hipFuncAttributeMaxDynamicSharedMemorySize, MLP_LDS);

    // prepack weights (batched over grid.y) + combined edge tables
    k_pack<<<dim3(480, 1), 256, 0, stream>>>(out_lin_w, OLWP, 300, 300, 10, 384,
                                             0, 0);
    k_pack<<<dim3(800, LL), 256, 0, stream>>>(mlp_w1, W1P, DD, D2, 10, 640,
                                              (size_t)DD * D2, (size_t)10 * 640 * 32);
    k_pack<<<dim3(912, LL), 256, 0, stream>>>(mlp_w2, W2P, D2, DD, 19, 384,
                                              (size_t)D2 * DD, (size_t)19 * 384 * 32);
    k_etab<<<(LL * 25 * DD + 255) / 256, 256, 0, stream>>>(edge_emb, ETAB);
    hipMemsetAsync(REPS, 0, (size_t)LL * 2 * 32 * 600 * 4, stream);

    // CSR build
    hipMemsetAsync(DEG, 0, (size_t)NN * 4, stream);
    k_degree<<<(EE + 255) / 256, 256, 0, stream>>>(dstp, DEG);
    k_scan1<<<391, 256, 0, stream>>>(DEG, OFF, BSUM);
    k_scan2<<<1, 512, 0, stream>>>(BSUM, OFF, 391);
    k_scan3<<<391, 256, 0, stream>>>(OFF, BSUM, CURS);
    k_fill<<<(EE + 255) / 256, 256, 0, stream>>>(dstp, CURS, EIDX);

    // node init (QB aliases AGG)
    short* QB = (short*)AGG;
    k_embed<<<(NN + 3) / 4, 256, 0, stream>>>(x, atom_emb, att_vec, QB);
    k_g1<<<NN / 32, 256, 0, stream>>>(QB, OLWP, out_lin_b, H);
    k_gaussg<<<(NN + 3) / 4, 320, 0, stream>>>(OFF, EIDX, edge_dist, g_means,
                                               g_stds, scale_p, H);
    k_repack<<<(EE + 255) / 256, 256, 0, stream>>>(EIDX, srcp, edge_attr);

    // layer loop: P stored bf16 (aliases H buffer) for l<4, fp32 H for l=4
    for (int l = 0; l < LL; l++) {
        const float* sc = SCL + (size_t)(l - 1) * 1200;   // valid only l>0
        k_agg<<<(NN + 3) / 4, 320, 0, stream>>>(
            (const void*)H, OFF, EIDX, ETAB + (size_t)l * 25 * DD,
            l > 0 ? sc : SCL, l > 0 ? sc + 600 : SCL, l > 0 ? 1 : 0, QB);
        k_mlp2<<<(NN + RPB - 1) / RPB, 512, MLP_LDS, stream>>>(
            QB, W1P + (size_t)l * 10 * 640 * 32, mlp_b1 + (size_t)l * D2,
            W2P + (size_t)l * 19 * 384 * 32, mlp_b2 + (size_t)l * DD,
            (void*)H, (l < LL - 1) ? 1 : 0,
            REPS + (size_t)l * 38400);
        k_bnprep<<<2, 256, 0, stream>>>(REPS + (size_t)l * 38400,
                                        SCL + (size_t)l * 1200,
                                        bn_gamma + (size_t)l * DD,
                                        bn_beta + (size_t)l * DD);
    }

    // pooling (count fused into k_pool); last BN folded into k_hgdiv
    hipMemsetAsync(CNT, 0, (size_t)GG * 4, stream);
    hipMemsetAsync(HG, 0, (size_t)GG * DD * 4, stream);
    k_pool<<<(NN + ROWS_PER - 1) / ROWS_PER, 320, 0, stream>>>(H, batch, HG, CNT);
    k_hgdiv<<<(GG * DD + 255) / 256, 256, 0, stream>>>(HG, CNT,
                                                       SCL + (size_t)4 * 1200);
    {
        dim3 grid((FEATN + 63) / 64, (GG + 15) / 16);
        k_gemm<<<grid, 256, 0, stream>>>(HG, feat_w, feat_b, HFEAT, outp,
                                         GG, DD, FEATN, 0);
    }
    {
        dim3 grid((FEATN + 63) / 64, (GG + 15) / 16);
        k_gemm<<<grid, 256, 0, stream>>>(HFEAT, ol_w1, ol_b1, TMP, nullptr,
                                         GG, FEATN, FEATN, 1);
    }
    {
        dim3 grid((OUT2 + 63) / 64, (GG + 15) / 16);
        k_gemm<<<grid, 256, 0, stream>>>(TMP, ol_w2, ol_b2, nullptr,
                                         outp + (size_t)GG * FEATN,
                                         GG, FEATN, OUT2, 0);
    }
}

// Round 15
// 1647.523 us; speedup vs baseline: 1.1043x; 1.0013x over previous
//
#include <hip/hip_runtime.h>
#include <hip/hip_bf16.h>

// GINet forward, fp32 in/out. R29 = R28 (1650us best) + launch-path micro-
// bundle: (1) k_hgdiv folded into head GEMM #1 (A-staging applies
// (HG/max(cnt,1))*SC+shift; padded Ash entries never read, transform only on
// in-range elements) — one 2.4MB pass + 1 dispatch gone; (2) CNT+HG memsets
// merged (adjacent in ws; CNT rounds to 8192B); (3) k_scan1 shfl scan (2
// barriers vs 16). k_mlp2 / k_agg / k_gaussg / k_embed / k_g1 byte-identical
// to R28 (all at verified structural floors).

#define NN   100000
#define EE   200000
#define GG   2000
#define DD   300
#define D2   600
#define LL   5
#define FEATN 512
#define OUT2 256
#define ROWS_PER 256
#define RPB  48          // rows per k_mlp2 block
#define MLP_LDS (RPB * 632 * 2)   // 60,672 B -> 2 blocks/CU

typedef __hip_bfloat16 bf16;
typedef short vec8s __attribute__((ext_vector_type(8)));
typedef short vec4s __attribute__((ext_vector_type(4)));
typedef float vec4f __attribute__((ext_vector_type(4)));

__device__ __forceinline__ short f2bs(float v) {
    bf16 h = __float2bfloat16(v);
    return __builtin_bit_cast(short, h);
}
__device__ __forceinline__ float bs2f(short s) {
    unsigned u = ((unsigned)(unsigned short)s) << 16;
    return __builtin_bit_cast(float, u);
}

// ---- weight prepack: src[K][N] fp32 -> dst[kt][col<NPAD][32] bf16 ----
// batched over blockIdx.y (layer); strides in elements
__global__ void k_pack(const float* __restrict__ src0, short* __restrict__ dst0,
                       int Ksrc, int Nsrc, int KT, int NPAD,
                       size_t sstride, size_t dstride)
{
    const float* src = src0 + (size_t)blockIdx.y * sstride;
    short* dst = dst0 + (size_t)blockIdx.y * dstride;
    int idx = blockIdx.x * 256 + threadIdx.x;
    int total = KT * NPAD * 32;
    if (idx >= total) return;
    int col = idx % NPAD;
    int tmp = idx / NPAD;
    int kk  = tmp % 32;
    int kt  = tmp / 32;
    int k = kt * 32 + kk;
    short v = 0;
    if (k < Ksrc && col < Nsrc) v = f2bs(src[(size_t)k * Nsrc + col]);
    dst[((size_t)kt * NPAD + col) * 32 + kk] = v;
}

// ---- combined edge-emb tables: E[l][c][d], c<24 = a0*6+a1*2+a2, c==24 self ----
__global__ void k_etab(const float* __restrict__ edge_emb, float* __restrict__ E)
{
    int i = blockIdx.x * 256 + threadIdx.x;
    if (i >= LL * 25 * DD) return;
    int d = i % DD;
    int t = i / DD;
    int c = t % 25;
    int l = t / 25;
    int a0 = (c == 24) ? 4 : (c / 6);
    int a1 = (c == 24) ? 0 : ((c % 6) / 2);
    int a2 = (c == 24) ? 0 : (c % 2);
    const float* e0 = edge_emb + (size_t)((l * 3 + 0) * 5) * DD;
    const float* e1 = edge_emb + (size_t)((l * 3 + 1) * 5) * DD;
    const float* e2 = edge_emb + (size_t)((l * 3 + 2) * 5) * DD;
    E[i] = e0[a0 * DD + d] + e1[a1 * DD + d] + e2[a2 * DD + d];
}

// ---- repack EIDX: edge id -> src | (combo<<17) ----
__global__ void k_repack(int* __restrict__ eidx, const int* __restrict__ src,
                         const int* __restrict__ attr)
{
    int i = blockIdx.x * 256 + threadIdx.x;
    if (i >= EE) return;
    int e = eidx[i];
    int c = attr[e * 3] * 6 + attr[e * 3 + 1] * 2 + attr[e * 3 + 2];
    eidx[i] = src[e] | (c << 17);
}

// ---- fused MLP layer + replicated BN stats; 48 rows/block, 8 waves ----
__global__ __launch_bounds__(512, 4) void k_mlp2(
    const short* __restrict__ Qb, const short* __restrict__ W1P,
    const float* __restrict__ b1, const short* __restrict__ W2P,
    const float* __restrict__ b2, void* __restrict__ Pout, int f16out,
    float* __restrict__ RS)            // [2][32][600] partial sums for layer
{
    extern __shared__ __align__(16) char smem_c[];
    short* Apan = (short*)smem_c;                 // 48 rows x 320 shorts, swizzled
    short (*Hl)[632] = (short(*)[632])smem_c;     // overlaps Apan (A dead first)

    const int t = threadIdx.x;
    const int wv = t >> 6, lane = t & 63;
    const int m = lane & 15, quad = lane >> 4;
    const int rb = (int)blockIdx.x * RPB;
    const int rep = ((int)blockIdx.x & 31) * 600;

    // ---- stage A-panel: global_load_lds, source-swizzled (chunk ^= row&7) ----
    {
        const short* qbase = Qb + (size_t)rb * 320;
#pragma unroll
        for (int i = 0; i < 4; i++) {
            int j = i * 8 + wv;                       // 1KB issue index, j < 30
            if (j < 30) {
                int c   = j * 64 + lane;              // 16B chunk index
                int c8  = c >> 3;
                int row = c8 / 5;
                int ch  = (c8 - row * 5) * 8 + (lane & 7);
                const short* src = qbase + (size_t)row * 320
                                 + (size_t)((ch ^ (row & 7)) * 8);
                __builtin_amdgcn_global_load_lds(
                    (const __attribute__((address_space(1))) unsigned int*)src,
                    (__attribute__((address_space(3))) unsigned int*)(smem_c + j * 1024),
                    16, 0, 0);
            }
        }
    }

    // per-lane swizzled A-read bases (shorts): parity-split on eh = (m>>2)&1
    const int ql   = quad ^ (m & 3);
    const int eh   = (m >> 2) & 1;
    const int abE  = m * 320 + ql * 8 + eh * 32;        // even kt base
    const int abO  = m * 320 + ql * 8 + (1 - eh) * 32;  // odd kt base

    vec4f acc1[3][5];
#pragma unroll
    for (int g = 0; g < 3; g++)
#pragma unroll
        for (int cf = 0; cf < 5; cf++) acc1[g][cf] = (vec4f)0.f;

    // ---- stage 1: Hl = relu(Qb @ W1 + b1), operand-swapped MFMA ----
    const short* w1b = W1P + ((size_t)(wv * 80 + m) * 32) + quad * 8;
    vec8s bcur[5], bnxt[5];
#pragma unroll
    for (int cf = 0; cf < 5; cf++) bcur[cf] = *(const vec8s*)(w1b + cf * 512);

    __syncthreads();   // A-panel DMA drained (vmcnt0 at barrier)

#pragma unroll
    for (int kt = 0; kt < 10; kt++) {
        if (kt < 9) {
            const short* wn = w1b + (size_t)(kt + 1) * 20480;
#pragma unroll
            for (int cf = 0; cf < 5; cf++) bnxt[cf] = *(const vec8s*)(wn + cf * 512);
        }
        const int base = (kt & 1) ? abO : abE;
        const int koff = (kt & ~1) * 32;
        vec8s af[3];
#pragma unroll
        for (int g = 0; g < 3; g++)
            af[g] = *(const vec8s*)(Apan + base + koff + g * 5120);
        __builtin_amdgcn_s_setprio(1);
#pragma unroll
        for (int cf = 0; cf < 5; cf++)
#pragma unroll
            for (int g = 0; g < 3; g++)
                acc1[g][cf] = __builtin_amdgcn_mfma_f32_16x16x32_bf16(
                    bcur[cf], af[g], acc1[g][cf], 0, 0, 0);
        __builtin_amdgcn_s_setprio(0);
#pragma unroll
        for (int cf = 0; cf < 5; cf++) bcur[cf] = bnxt[cf];
    }

    // prefetch stage-2 B tiles 0 and 1 (global, independent of LDS)
    const short* w2b = W2P + ((size_t)(wv * 48 + m) * 32) + quad * 8;
    vec8s b2f[2][3];
#pragma unroll
    for (int cf = 0; cf < 3; cf++) {
        b2f[0][cf] = *(const vec8s*)(w2b + cf * 512);
        b2f[1][cf] = *(const vec8s*)(w2b + 12288 + cf * 512);
    }

    __syncthreads();   // all A-panel reads done before Hl overwrites region

    // stage-1 epilogue: bias+relu+bf16; lane holds 4 consecutive cols of a row
#pragma unroll
    for (int g = 0; g < 3; g++) {
#pragma unroll
        for (int cf = 0; cf < 5; cf++) {
            const int col0 = wv * 80 + cf * 16 + quad * 4;
            if (col0 < 600) {
                vec4f bv = *(const vec4f*)(b1 + col0);
                vec4s o;
#pragma unroll
                for (int r = 0; r < 4; r++)
                    o[r] = f2bs(fmaxf(acc1[g][cf][r] + bv[r], 0.f));
                *(vec4s*)&Hl[g * 16 + m][col0] = o;
            } else if (col0 < 608) {
                *(vec4s*)&Hl[g * 16 + m][col0] = (vec4s)0;
            }
        }
    }
    __syncthreads();

    // ---- stage 2 + stats into replica; staged coalesced P write ----
    {
        vec4f acc2[3][3];
#pragma unroll
        for (int g = 0; g < 3; g++)
#pragma unroll
            for (int cf = 0; cf < 3; cf++) acc2[g][cf] = (vec4f)0.f;

#pragma unroll
        for (int kt = 0; kt < 19; kt++) {
            vec8s ha[3];
#pragma unroll
            for (int g = 0; g < 3; g++)
                ha[g] = *(const vec8s*)&Hl[g * 16 + m][kt * 32 + quad * 8];
            __builtin_amdgcn_s_setprio(1);
#pragma unroll
            for (int cf = 0; cf < 3; cf++)
#pragma unroll
                for (int g = 0; g < 3; g++)
                    acc2[g][cf] = __builtin_amdgcn_mfma_f32_16x16x32_bf16(
                        ha[g], b2f[kt & 1][cf], acc2[g][cf], 0, 0, 0);
            __builtin_amdgcn_s_setprio(0);
            if (kt < 17) {
                const short* wn = w2b + (size_t)(kt + 2) * 12288;
#pragma unroll
                for (int cf = 0; cf < 3; cf++)
                    b2f[kt & 1][cf] = *(const vec8s*)(wn + cf * 512);
            }
        }

        __syncthreads();   // Hl reads complete; region reused for staged P

        short* Ps  = (short*)smem_c;   // [48][300] bf16 (28.8KB)
        float* Pw  = (float*)smem_c;   // [48][300] fp32 (57.6KB <= 60.6KB)

#pragma unroll
        for (int cf = 0; cf < 3; cf++) {
            int gc = wv * 48 + cf * 16 + m;
            bool ok = (gc < DD);
            float bv = ok ? b2[gc] : 0.f;
            float s = 0.f, q = 0.f;
#pragma unroll
            for (int g = 0; g < 3; g++) {
#pragma unroll
                for (int reg = 0; reg < 4; reg++) {
                    int rl = g * 16 + quad * 4 + reg;
                    bool vr = (rb + rl) < NN;
                    float v = acc2[g][cf][reg] + bv;
                    if (ok) {
                        if (f16out) Ps[rl * 300 + gc] = f2bs(v);
                        else        Pw[rl * 300 + gc] = v;
                    }
                    if (vr) { s += v; q += v * v; }
                }
            }
            s += __shfl_xor(s, 16); s += __shfl_xor(s, 32);
            q += __shfl_xor(q, 16); q += __shfl_xor(q, 32);
            if (ok && quad == 0) {
                atomicAdd(&RS[rep + gc], s);
                atomicAdd(&RS[19200 + rep + gc], q);
            }
        }
        __syncthreads();

        // coalesced linear copy LDS -> Pout (block's rows are contiguous)
        int nrows = NN - rb; if (nrows > RPB) nrows = RPB;
        if (f16out) {
            int total8 = nrows * 300 / 8;
            short* dst = (short*)Pout + (size_t)rb * 300;
            for (int i = t; i < total8; i += 512)
                *(vec8s*)(dst + i * 8) = *(const vec8s*)(Ps + i * 8);
        } else {
            int total4 = nrows * 300 / 4;
            float* dst = (float*)Pout + (size_t)rb * 300;
            for (int i = t; i < total4; i += 512)
                *(vec4f*)(dst + i * 4) = *(const vec4f*)(Pw + i * 4);
        }
    }
}

// ---- embed GEMM, stage1 shape with A+B double-buffer: H = Qb @ OLWP + b ----
__global__ __launch_bounds__(256) void k_g1(
    const short* __restrict__ Qb, const short* __restrict__ WP,
    const float* __restrict__ bias, float* __restrict__ H)
{
    const int t = threadIdx.x;
    const int wv = t >> 6, lane = t & 63;
    const int m = lane & 15, quad = lane >> 4;
    const int rb = (int)blockIdx.x * 32;
    const short* arow0 = Qb + (size_t)(rb + m) * 320 + quad * 8;
    const short* arow1 = arow0 + (size_t)16 * 320;
    const short* wb0 = WP + ((size_t)(wv * 80 + m) * 32) + quad * 8;

    vec4f acc[2][5];
#pragma unroll
    for (int g = 0; g < 2; g++)
#pragma unroll
        for (int cf = 0; cf < 5; cf++) acc[g][cf] = (vec4f)0.f;

    vec8s af0 = *(const vec8s*)arow0;
    vec8s af1 = *(const vec8s*)arow1;
    vec8s bcur[5], bnxt[5];
#pragma unroll
    for (int cf = 0; cf < 5; cf++) bcur[cf] = *(const vec8s*)(wb0 + cf * 512);

#pragma unroll
    for (int kt = 0; kt < 10; kt++) {
        vec8s an0 = af0, an1 = af1;
        if (kt < 9) {
            an0 = *(const vec8s*)(arow0 + (kt + 1) * 32);
            an1 = *(const vec8s*)(arow1 + (kt + 1) * 32);
            const short* wn = wb0 + (size_t)(kt + 1) * 12288;
#pragma unroll
            for (int cf = 0; cf < 5; cf++) bnxt[cf] = *(const vec8s*)(wn + cf * 512);
        }
#pragma unroll
        for (int cf = 0; cf < 5; cf++) {
            acc[0][cf] = __builtin_amdgcn_mfma_f32_16x16x32_bf16(af0, bcur[cf], acc[0][cf], 0, 0, 0);
            acc[1][cf] = __builtin_amdgcn_mfma_f32_16x16x32_bf16(af1, bcur[cf], acc[1][cf], 0, 0, 0);
        }
        af0 = an0; af1 = an1;
#pragma unroll
        for (int cf = 0; cf < 5; cf++) bcur[cf] = bnxt[cf];
    }
#pragma unroll
    for (int cf = 0; cf < 5; cf++) {
        int gc = wv * 80 + cf * 16 + m;
        if (gc >= DD) continue;
        float bv = bias[gc];
#pragma unroll
        for (int g = 0; g < 2; g++)
#pragma unroll
            for (int reg = 0; reg < 4; reg++)
                H[(size_t)(rb + g * 16 + quad * 4 + reg) * DD + gc] = acc[g][cf][reg] + bv;
    }
}

// ============ CSR build ============
__global__ void k_degree(const int* __restrict__ dst, int* __restrict__ deg) {
    int e = blockIdx.x * 256 + threadIdx.x;
    if (e < EE) atomicAdd(&deg[dst[e]], 1);
}

// 256-thread shfl scan (2 barriers)
__global__ void k_scan1(const int* __restrict__ deg, int* __restrict__ off,
                        int* __restrict__ bsum)
{
    __shared__ int wsum[4];
    int t = threadIdx.x, lane = t & 63, w = t >> 6;
    int i = blockIdx.x * 256 + t;
    int v = (i < NN) ? deg[i] : 0;
    int s = v;
    for (int o = 1; o < 64; o <<= 1) {
        int u = __shfl_up(s, o, 64);
        if (lane >= o) s += u;
    }
    if (lane == 63) wsum[w] = s;
    __syncthreads();
    if (t < 4) {
        int a = wsum[t];
        for (int o = 1; o < 4; o <<= 1) {
            int u = __shfl_up(a, o, 64);
            if (t >= o) a += u;
        }
        wsum[t] = a;
    }
    __syncthreads();
    int base = w ? wsum[w - 1] : 0;
    int incl = s + base;
    if (i < NN) off[i] = incl - v;           // exclusive within block
    if (t == 255) bsum[blockIdx.x] = incl;   // block total
}

// parallel scan over nb (<512) block sums: one 512-thread block
__global__ void k_scan2(int* __restrict__ bsum, int* __restrict__ off, int nb) {
    __shared__ int ws[8];
    int t = threadIdx.x;
    int v = (t < nb) ? bsum[t] : 0;
    int s = v;
    for (int o = 1; o < 64; o <<= 1) {
        int u = __shfl_up(s, o, 64);
        if ((t & 63) >= o) s += u;
    }
    if ((t & 63) == 63) ws[t >> 6] = s;
    __syncthreads();
    if (t < 8) {
        int a = ws[t];
        for (int o = 1; o < 8; o <<= 1) {
            int u = __shfl_up(a, o, 64);
            if (t >= o) a += u;
        }
        ws[t] = a;
    }
    __syncthreads();
    int base = (t >> 6) ? ws[(t >> 6) - 1] : 0;
    int incl = s + base;
    if (t < nb) bsum[t] = incl - v;      // exclusive
    if (t == nb - 1) off[NN] = incl;     // total
}

__global__ void k_scan3(int* __restrict__ off, const int* __restrict__ bsum,
                        int* __restrict__ curs)
{
    int i = blockIdx.x * 256 + threadIdx.x;
    if (i >= NN) return;
    int v = off[i] + bsum[i >> 8];
    off[i] = v;
    curs[i] = v;
}

__global__ void k_fill(const int* __restrict__ dst, int* __restrict__ curs,
                       int* __restrict__ eidx)
{
    int e = blockIdx.x * 256 + threadIdx.x;
    if (e >= EE) return;
    int pos = atomicAdd(&curs[dst[e]], 1);
    eidx[pos] = e;
}

// ============ embed attention -> bf16 rows (stride 320, pads zeroed) ============
__global__ __launch_bounds__(256) void k_embed(
    const int* __restrict__ x, const float* __restrict__ atom_emb,
    const float* __restrict__ att_vec, short* __restrict__ fusedb)
{
    int wave = threadIdx.x >> 6;
    int lane = threadIdx.x & 63;
    int n = blockIdx.x * 4 + wave;
    if (n >= NN) return;

    float att[5];
#pragma unroll
    for (int j = 0; j < 5; j++) {
        int d = lane + 64 * j;
        att[j] = (d < DD) ? att_vec[d] : 0.f;
    }
    float emb[9][5];
    float sc[9];
#pragma unroll
    for (int f = 0; f < 9; f++) {
        int idx = x[n * 9 + f];
        const float* p = atom_emb + (size_t)(f * 119 + idx) * DD;
        float partial = 0.f;
#pragma unroll
        for (int j = 0; j < 5; j++) {
            int d = lane + 64 * j;
            float v = (d < DD) ? p[d] : 0.f;
            emb[f][j] = v;
            partial += v * att[j];
        }
#pragma unroll
        for (int off = 32; off; off >>= 1) partial += __shfl_xor(partial, off, 64);
        sc[f] = partial;
    }
    float mx = sc[0];
#pragma unroll
    for (int f = 1; f < 9; f++) mx = fmaxf(mx, sc[f]);
    float s = 0.f;
#pragma unroll
    for (int f = 0; f < 9; f++) { sc[f] = __expf(sc[f] - mx); s += sc[f]; }
    float inv = 1.f / s;
#pragma unroll
    for (int j = 0; j < 5; j++) {
        int d = lane + 64 * j;
        float acc = 0.f;
        if (d < DD) {
#pragma unroll
            for (int f = 0; f < 9; f++) acc += emb[f][j] * sc[f];
            acc *= inv;
        }
        fusedb[(size_t)n * 320 + d] = (d < DD) ? f2bs(acc) : (short)0;
    }
}

// ---- gaussian basis: 4 nodes/block x 80 thr, d4 grain ----
__global__ __launch_bounds__(320) void k_gaussg(
    const int* __restrict__ off, const int* __restrict__ eidx,
    const float* __restrict__ dist, const float* __restrict__ g_means,
    const float* __restrict__ g_stds, const float* __restrict__ scale_p,
    float* __restrict__ H)
{
    int tn = threadIdx.x / 80;
    int td = threadIdx.x - tn * 80;
    int n = blockIdx.x * 4 + tn;
    if (n >= NN) return;
    int d4 = td * 4;
    if (d4 >= DD) return;
    int beg = off[n], end = off[n + 1];
    if (beg == end) return;
    vec4f gs = *(const vec4f*)(g_stds + d4);
    vec4f gm = *(const vec4f*)(g_means + d4);
    float sd[4], mean[4], inva[4], sum[4];
#pragma unroll
    for (int j = 0; j < 4; j++) {
        sd[j] = fabsf(gs[j]) + 0.01f;
        mean[j] = gm[j];
        inva[j] = 1.f / (2.5066263f * sd[j]);
        sum[j] = 0.f;
    }
    for (int i = beg; i < end; i++) {
        float xv = dist[eidx[i]];
#pragma unroll
        for (int j = 0; j < 4; j++) {
            float z = (xv - mean[j]) / sd[j];
            sum[j] += __expf(-0.5f * z * z) * inva[j];
        }
    }
    int deg = end - beg;
    int c = deg - 1; c = c < 0 ? 0 : (c > 3 ? 3 : c);
    vec4f sp = *(const vec4f*)(scale_p + c * DD + d4);
    float* hp = H + (size_t)n * DD + d4;
    vec4f hv = *(const vec4f*)hp;
#pragma unroll
    for (int j = 0; j < 4; j++) hv[j] += __expf(sp[j]) * sum[j];
    *(vec4f*)hp = hv;
}

// ---- fused aggregation: 4 nodes/block x 80 thr, short4 grain, 2-edge
//      batched gather issue. apply=0: fp32 P, apply=1: bf16 P ----
__global__ __launch_bounds__(320) void k_agg(
    const void* __restrict__ P, const int* __restrict__ off,
    const int* __restrict__ eidxp, const float* __restrict__ E,
    const float* __restrict__ scale, const float* __restrict__ shift,
    int apply, short* __restrict__ Qb)
{
    int tn = threadIdx.x / 80;
    int td = threadIdx.x - tn * 80;
    int n = blockIdx.x * 4 + tn;
    if (n >= NN) return;
    int d4 = td * 4;
    if (d4 >= DD) {   // cols 300..316 -> zero pads (covers 300..319)
        *(vec4s*)&Qb[(size_t)n * 320 + d4] = (vec4s)0;
        return;
    }
    const float* Pf = (const float*)P;
    const short* Ph = (const short*)P;

    float a[4];
    float sc[4], sh[4];
    if (apply) {
        vec4f s4 = *(const vec4f*)(scale + d4);
        vec4f h4 = *(const vec4f*)(shift + d4);
#pragma unroll
        for (int j = 0; j < 4; j++) { sc[j] = s4[j]; sh[j] = h4[j]; }
        vec4s pv = *(const vec4s*)(Ph + (size_t)n * 300 + d4);
#pragma unroll
        for (int j = 0; j < 4; j++)
            a[j] = fmaxf(bs2f(pv[j]) * sc[j] + sh[j], 0.f);
    } else {
        vec4f self = *(const vec4f*)(Pf + (size_t)n * DD + d4);
#pragma unroll
        for (int j = 0; j < 4; j++) a[j] = self[j];
    }
    {
        vec4f es = *(const vec4f*)(E + 24 * DD + d4);
#pragma unroll
        for (int j = 0; j < 4; j++) a[j] += es[j];
    }

    int beg = off[n], end = off[n + 1];
    int i = beg;
    if (apply) {
        for (; i + 1 < end; i += 2) {
            int v0 = eidxp[i], v1 = eidxp[i + 1];
            int s0 = v0 & 131071, c0 = v0 >> 17;
            int s1 = v1 & 131071, c1 = v1 >> 17;
            vec4s p0 = *(const vec4s*)(Ph + (size_t)s0 * 300 + d4);
            vec4s p1 = *(const vec4s*)(Ph + (size_t)s1 * 300 + d4);
            vec4f e0 = *(const vec4f*)(E + c0 * DD + d4);
            vec4f e1 = *(const vec4f*)(E + c1 * DD + d4);
#pragma unroll
            for (int j = 0; j < 4; j++)
                a[j] += fmaxf(bs2f(p0[j]) * sc[j] + sh[j], 0.f) + e0[j];
#pragma unroll
            for (int j = 0; j < 4; j++)
                a[j] += fmaxf(bs2f(p1[j]) * sc[j] + sh[j], 0.f) + e1[j];
        }
        if (i < end) {
            int v0 = eidxp[i];
            int s0 = v0 & 131071, c0 = v0 >> 17;
            vec4s p0 = *(const vec4s*)(Ph + (size_t)s0 * 300 + d4);
            vec4f e0 = *(const vec4f*)(E + c0 * DD + d4);
#pragma unroll
            for (int j = 0; j < 4; j++)
                a[j] += fmaxf(bs2f(p0[j]) * sc[j] + sh[j], 0.f) + e0[j];
        }
    } else {
        for (; i + 1 < end; i += 2) {
            int v0 = eidxp[i], v1 = eidxp[i + 1];
            int s0 = v0 & 131071, c0 = v0 >> 17;
            int s1 = v1 & 131071, c1 = v1 >> 17;
            vec4f p0 = *(const vec4f*)(Pf + (size_t)s0 * DD + d4);
            vec4f p1 = *(const vec4f*)(Pf + (size_t)s1 * DD + d4);
            vec4f e0 = *(const vec4f*)(E + c0 * DD + d4);
            vec4f e1 = *(const vec4f*)(E + c1 * DD + d4);
#pragma unroll
            for (int j = 0; j < 4; j++) a[j] += p0[j] + e0[j];
#pragma unroll
            for (int j = 0; j < 4; j++) a[j] += p1[j] + e1[j];
        }
        if (i < end) {
            int v0 = eidxp[i];
            int s0 = v0 & 131071, c0 = v0 >> 17;
            vec4f p0 = *(const vec4f*)(Pf + (size_t)s0 * DD + d4);
            vec4f e0 = *(const vec4f*)(E + c0 * DD + d4);
#pragma unroll
            for (int j = 0; j < 4; j++) a[j] += p0[j] + e0[j];
        }
    }
    vec4s o;
#pragma unroll
    for (int j = 0; j < 4; j++) o[j] = f2bs(a[j]);
    *(vec4s*)&Qb[(size_t)n * 320 + d4] = o;
}

// ---- reduce 32 replicas -> scale/shift for the layer ----
__global__ void k_bnprep(const float* __restrict__ RS, float* __restrict__ SC,
                         const float* __restrict__ gamma,
                         const float* __restrict__ beta)
{
    int d = threadIdx.x + blockIdx.x * 256;
    if (d >= DD) return;
    float s = 0.f, q = 0.f;
    for (int r = 0; r < 32; r++) {
        s += RS[r * 600 + d];
        q += RS[19200 + r * 600 + d];
    }
    float mu = s * (1.f / NN);
    float var = q * (1.f / NN) - mu * mu;
    var = fmaxf(var, 0.f);
    float sc = gamma[d] * rsqrtf(var + 1e-5f);
    SC[d] = sc;
    SC[600 + d] = beta[d] - mu * sc;
}

// ============ pooling (with fused run-length counting) + head ============
__global__ __launch_bounds__(320) void k_pool(const float* __restrict__ H,
                                              const int* __restrict__ batch,
                                              float* __restrict__ HG,
                                              float* __restrict__ cnt)
{
    __shared__ int sb[ROWS_PER];
    int r0 = blockIdx.x * ROWS_PER;
    int rend = min(r0 + ROWS_PER, NN);
    for (int i = threadIdx.x; i < rend - r0; i += 320) sb[i] = batch[r0 + i];
    __syncthreads();
    int d = threadIdx.x;
    if (d >= DD) return;
    int cur = sb[0];
    float acc = 0.f;
    int run = 0;
    for (int r = r0; r < rend; r++) {
        int b = sb[r - r0];
        if (b != cur) {
            atomicAdd(&HG[(size_t)cur * DD + d], acc);
            if (d == 0) atomicAdd(&cnt[cur], (float)run);
            acc = 0.f; run = 0; cur = b;
        }
        acc += H[(size_t)r * DD + d];
        run++;
    }
    atomicAdd(&HG[(size_t)cur * DD + d], acc);
    if (d == 0) atomicAdd(&cnt[cur], (float)run);
}

// ---- head GEMM: 16x64 tile, 1x4 outputs/thread; optional fused BN/mean
//      transform on A (xs = SC scale/shift table, xc = counts) ----
__global__ __launch_bounds__(256) void k_gemm(
    const float* __restrict__ A, const float* __restrict__ W,
    const float* __restrict__ bias, float* __restrict__ Cf,
    float* __restrict__ Cout, int M, int K, int Ncol, int relu,
    const float* __restrict__ xs, const float* __restrict__ xc)
{
    __shared__ float Ash[16][33];
    const int tx = threadIdx.x & 15;        // col group (float4)
    const int ty = threadIdx.x >> 4;        // row 0..15
    const int rb = blockIdx.y * 16;
    const int col = blockIdx.x * 64 + tx * 4;

    float acc[4] = {0.f, 0.f, 0.f, 0.f};

    for (int k0 = 0; k0 < K; k0 += 32) {
        // stage A[rb..rb+16)[k0..k0+32) -> Ash (256 thr x 2 floats)
        {
            int r  = threadIdx.x >> 4;
            int kk = (threadIdx.x & 15) * 2;
            int row = rb + r;
            float vx = 0.f, vy = 0.f;
            if (row < M) {
                const float* ap = A + (size_t)row * K + k0 + kk;
                if (k0 + kk + 1 < K) {
                    float2 v = *(const float2*)ap;
                    vx = v.x; vy = v.y;
                    if (xs) {
                        float ic = 1.f / fmaxf(xc[row], 1.f);
                        vx = vx * ic * xs[k0 + kk]     + xs[600 + k0 + kk];
                        vy = vy * ic * xs[k0 + kk + 1] + xs[600 + k0 + kk + 1];
                    }
                } else if (k0 + kk < K) {
                    vx = ap[0];
                    if (xs) {
                        float ic = 1.f / fmaxf(xc[row], 1.f);
                        vx = vx * ic * xs[k0 + kk] + xs[600 + k0 + kk];
                    }
                }
            }
            Ash[r][kk]     = vx;
            Ash[r][kk + 1] = vy;
        }
        __syncthreads();

        const int kmax = (K - k0 < 32) ? (K - k0) : 32;
        const float* wp = W + (size_t)k0 * Ncol + col;
#pragma unroll 4
        for (int k = 0; k < kmax; k++) {
            float4 wv = *(const float4*)(wp + (size_t)k * Ncol);
            float a = Ash[ty][k];
            acc[0] += a * wv.x; acc[1] += a * wv.y;
            acc[2] += a * wv.z; acc[3] += a * wv.w;
        }
        __syncthreads();
    }

    int row = rb + ty;
    if (row < M) {
        float4 bv = *(const float4*)(bias + col);
        float4 o;
        o.x = acc[0] + bv.x; o.y = acc[1] + bv.y;
        o.z = acc[2] + bv.z; o.w = acc[3] + bv.w;
        if (relu) {
            o.x = fmaxf(o.x, 0.f); o.y = fmaxf(o.y, 0.f);
            o.z = fmaxf(o.z, 0.f); o.w = fmaxf(o.w, 0.f);
        }
        if (Cf)   *(float4*)(Cf   + (size_t)row * Ncol + col) = o;
        if (Cout) *(float4*)(Cout + (size_t)row * Ncol + col) = o;
    }
}

extern "C" void kernel_launch(void* const* d_in, const int* in_sizes, int n_in,
                              void* d_out, int out_size, void* d_ws, size_t ws_size,
                              hipStream_t stream)
{
    const int*   x          = (const int*)  d_in[0];
    const int*   edge_index = (const int*)  d_in[1];
    const int*   edge_attr  = (const int*)  d_in[2];
    const float* edge_dist  = (const float*)d_in[3];
    const int*   batch      = (const int*)  d_in[4];
    const float* atom_emb   = (const float*)d_in[5];
    const float* att_vec    = (const float*)d_in[6];
    const float* out_lin_w  = (const float*)d_in[7];
    const float* out_lin_b  = (const float*)d_in[8];
    const float* g_means    = (const float*)d_in[9];
    const float* g_stds     = (const float*)d_in[10];
    const float* scale_p    = (const float*)d_in[11];
    const float* edge_emb   = (const float*)d_in[12];
    const float* mlp_w1     = (const float*)d_in[13];
    const float* mlp_b1     = (const float*)d_in[14];
    const float* mlp_w2     = (const float*)d_in[15];
    const float* mlp_b2     = (const float*)d_in[16];
    const float* bn_gamma   = (const float*)d_in[17];
    const float* bn_beta    = (const float*)d_in[18];
    const float* feat_w     = (const float*)d_in[19];
    const float* feat_b     = (const float*)d_in[20];
    const float* ol_w1      = (const float*)d_in[21];
    const float* ol_b1      = (const float*)d_in[22];
    const float* ol_w2      = (const float*)d_in[23];
    const float* ol_b2      = (const float*)d_in[24];
    (void)in_sizes; (void)n_in; (void)out_size; (void)ws_size;

    const int* srcp = edge_index;
    const int* dstp = edge_index + EE;

    char* ws = (char*)d_ws;
    size_t off_b = 0;
    auto alloc = [&](size_t bytes) -> char* {
        char* p = ws + off_b;
        off_b += (bytes + 255) & ~(size_t)255;
        return p;
    };
    float* H     = (float*)alloc((size_t)NN * DD * 4 + 256);
    float* AGG   = (float*)alloc((size_t)NN * DD * 4 + 256);
    int*   DEG   = (int*)  alloc((size_t)NN * 4);
    float* CNT   = (float*)alloc(GG * 4);                  // 8000 -> 8192 pad
    float* HG    = (float*)alloc((size_t)GG * DD * 4);     // contiguous w/ CNT
    float* HFEAT = (float*)alloc((size_t)GG * FEATN * 4);
    float* TMP   = (float*)alloc((size_t)GG * FEATN * 4);

    short* OLWP = (short*)HG;                        //   245,760 B
    short* W1P  = OLWP + (size_t)10 * 384 * 32;      // 2,048,000 B
    short* W2P  = W1P + (size_t)LL * 10 * 640 * 32;  // 2,334,720 B
    char*  csr  = (char*)(W2P + (size_t)LL * 19 * 384 * 32);
    int*   OFF  = (int*)csr;                         //   400,128
    int*   CURS = (int*)(csr + 400128);              //   400,128
    int*   EIDX = (int*)(csr + 800128);              //   800,128
    float* ETAB = (float*)(csr + 1600256);           //   150,000
    float* REPS = (float*)(csr + 1750272);           // 5*2*32*600*4 = 768,000
    float* SCL  = (float*)(csr + 2518528);           // 5*1200*4 = 24,000
    int*   BSUM = (int*)CNT;                         // end csr+2,542,528 <= pool

    float* outp = (float*)d_out;

    // allow dynamic LDS for k_mlp2 (60,672 B -> 2 blocks/CU)
    hipFuncSetAttribute((const void*)k_mlp2,
                        hipFuncAttributeMaxDynamicSharedMemorySize, MLP_LDS);

    // prepack weights (batched over grid.y) + combined edge tables
    k_pack<<<dim3(480, 1), 256, 0, stream>>>(out_lin_w, OLWP, 300, 300, 10, 384,
                                             0, 0);
    k_pack<<<dim3(800, LL), 256, 0, stream>>>(mlp_w1, W1P, DD, D2, 10, 640,
                                              (size_t)DD * D2, (size_t)10 * 640 * 32);
    k_pack<<<dim3(912, LL), 256, 0, stream>>>(mlp_w2, W2P, D2, DD, 19, 384,
                                              (size_t)D2 * DD, (size_t)19 * 384 * 32);
    k_etab<<<(LL * 25 * DD + 255) / 256, 256, 0, stream>>>(edge_emb, ETAB);
    hipMemsetAsync(REPS, 0, (size_t)LL * 2 * 32 * 600 * 4, stream);

    // CSR build
    hipMemsetAsync(DEG, 0, (size_t)NN * 4, stream);
    k_degree<<<(EE + 255) / 256, 256, 0, stream>>>(dstp, DEG);
    k_scan1<<<391, 256, 0, stream>>>(DEG, OFF, BSUM);
    k_scan2<<<1, 512, 0, stream>>>(BSUM, OFF, 391);
    k_scan3<<<391, 256, 0, stream>>>(OFF, BSUM, CURS);
    k_fill<<<(EE + 255) / 256, 256, 0, stream>>>(dstp, CURS, EIDX);

    // node init (QB aliases AGG)
    short* QB = (short*)AGG;
    k_embed<<<(NN + 3) / 4, 256, 0, stream>>>(x, atom_emb, att_vec, QB);
    k_g1<<<NN / 32, 256, 0, stream>>>(QB, OLWP, out_lin_b, H);
    k_gaussg<<<(NN + 3) / 4, 320, 0, stream>>>(OFF, EIDX, edge_dist, g_means,
                                               g_stds, scale_p, H);
    k_repack<<<(EE + 255) / 256, 256, 0, stream>>>(EIDX, srcp, edge_attr);

    // layer loop: P stored bf16 (aliases H buffer) for l<4, fp32 H for l=4
    for (int l = 0; l < LL; l++) {
        const float* sc = SCL + (size_t)(l - 1) * 1200;   // valid only l>0
        k_agg<<<(NN + 3) / 4, 320, 0, stream>>>(
            (const void*)H, OFF, EIDX, ETAB + (size_t)l * 25 * DD,
            l > 0 ? sc : SCL, l > 0 ? sc + 600 : SCL, l > 0 ? 1 : 0, QB);
        k_mlp2<<<(NN + RPB - 1) / RPB, 512, MLP_LDS, stream>>>(
            QB, W1P + (size_t)l * 10 * 640 * 32, mlp_b1 + (size_t)l * D2,
            W2P + (size_t)l * 19 * 384 * 32, mlp_b2 + (size_t)l * DD,
            (void*)H, (l < LL - 1) ? 1 : 0,
            REPS + (size_t)l * 38400);
        k_bnprep<<<2, 256, 0, stream>>>(REPS + (size_t)l * 38400,
                                        SCL + (size_t)l * 1200,
                                        bn_gamma + (size_t)l * DD,
                                        bn_beta + (size_t)l * DD);
    }

    // pooling; last BN + mean-divide fused into head GEMM #1's A transform
    hipMemsetAsync(CNT, 0, 8192 + (size_t)GG * DD * 4, stream);  // CNT+HG contiguous
    k_pool<<<(NN + ROWS_PER - 1) / ROWS_PER, 320, 0, stream>>>(H, batch, HG, CNT);
    {
        dim3 grid((FEATN + 63) / 64, (GG + 15) / 16);
        k_gemm<<<grid, 256, 0, stream>>>(HG, feat_w, feat_b, HFEAT, outp,
                                         GG, DD, FEATN, 0,
                                         SCL + (size_t)4 * 1200, CNT);
    }
    {
        dim3 grid((FEATN + 63) / 64, (GG + 15) / 16);
        k_gemm<<<grid, 256, 0, stream>>>(HFEAT, ol_w1, ol_b1, TMP, nullptr,
                                         GG, FEATN, FEATN, 1, nullptr, nullptr);
    }
    {
        dim3 grid((OUT2 + 63) / 64, (GG + 15) / 16);
        k_gemm<<<grid, 256, 0, stream>>>(TMP, ol_w2, ol_b2, nullptr,
                                         outp + (size_t)GG * FEATN,
                                         GG, FEATN, OUT2, 0, nullptr, nullptr);
    }
}